// Round 18
// baseline (392.035 us; speedup 1.0000x reference)
//
#include <hip/hip_runtime.h>
#include <hip/hip_bf16.h>

// ---------------- types / helpers ----------------
using bf16x8 = __attribute__((ext_vector_type(8))) short;
using f32x4  = __attribute__((ext_vector_type(4))) float;
using v2f    = __attribute__((ext_vector_type(2))) float;

__device__ __forceinline__ unsigned short f2bf_rne(float x) {
    unsigned u = __float_as_uint(x);
    u += 0x7fffu + ((u >> 16) & 1u);
    return (unsigned short)(u >> 16);
}

__device__ __forceinline__ void gload_lds16(const void* g, void* l) {
    __builtin_amdgcn_global_load_lds(
        (const __attribute__((address_space(1))) unsigned int*)g,
        (__attribute__((address_space(3))) unsigned int*)l, 16, 0, 0);
}

// K geometry: 8192 data k + 32 bias rows (fs x consq_b) + zero-pad -> 8320 = 2 x 65 x 64
constexpr int KP = 8320;
constexpr int KROW = KP * 2;

// ---------------- workspace layout (bytes) ----------------
constexpr size_t OFF_DT  = 0;                                  // [260][4096] f32 padded dataT
constexpr size_t OFF_Q1  = OFF_DT  + (size_t)260 * 4096 * 4;   // [32][4][256] f32 q1
constexpr size_t OFF_BT  = OFF_Q1  + (size_t)32 * 1024 * 4;    // [1024][KP] bf16 pre-swizzled B^T (+bias rows)
constexpr size_t OFF_C1P = OFF_BT;                             // [4][127][4096] float2 (aliases BT)
constexpr size_t OFF_W1S = OFF_BT  + (size_t)1024 * KP * 2;    // [128][256] bf16 pre-swizzled fc1_w
constexpr size_t OFF_FSI = OFF_W1S + (size_t)128 * 256 * 2;    // [131072] f32 fs_ini
constexpr size_t OFF_FS  = OFF_FSI + (size_t)32 * 4096 * 4;    // [32][4096] f32 fs^T
constexpr size_t OFF_ASC = OFF_FS  + (size_t)32 * 4096 * 4;    // [4096][KP] bf16 A
constexpr size_t OFF_P1  = OFF_ASC + (size_t)4096 * KP * 2;    // [4096][1000] f16 K-split partial
// total = ~98.9 MB

// ---------------- kernel: transpose data [4096][256] -> dTp rows 1..256 ----------------
__global__ __launch_bounds__(256) void k_transpose(const float* __restrict__ data,
                                                   float* __restrict__ dTp) {
    __shared__ float tile[64][65];
    int bx = blockIdx.x & 63;
    int fx = blockIdx.x >> 6;
    int tx = threadIdx.x & 63, ty4 = threadIdx.x >> 6;
#pragma unroll
    for (int i = 0; i < 16; ++i) {
        int ty = ty4 * 16 + i;
        tile[ty][tx] = data[(bx * 64 + ty) * 256 + fx * 64 + tx];
    }
    __syncthreads();
#pragma unroll
    for (int i = 0; i < 16; ++i) {
        int ty = ty4 * 16 + i;
        dTp[(size_t)(fx * 64 + ty + 1) * 4096 + bx * 64 + tx] = tile[tx][ty];
    }
}

__global__ __launch_bounds__(256) void k_zrows(float* __restrict__ dTp) {
    int i = blockIdx.x * 256 + threadIdx.x;
    dTp[i] = 0.f;
    dTp[(size_t)257 * 4096 + i] = 0.f;
}

// ---------------- kernel: q1 = conv1(proto) - b1 ----------------
__global__ __launch_bounds__(256) void k_prep_proto(const float* __restrict__ proto,
                                                    const float* __restrict__ w1,
                                                    const float* __restrict__ b1,
                                                    float* __restrict__ q1p) {
    __shared__ float ps[256];
    __shared__ float w1s[20];
    int r = blockIdx.x, tid = threadIdx.x;
    ps[tid] = proto[r * 256 + tid];
    if (tid < 20) w1s[tid] = w1[tid];
    __syncthreads();
    if (tid < 254) {
#pragma unroll
        for (int c = 0; c < 4; ++c) {
            float s = -b1[c];
#pragma unroll
            for (int k = 0; k < 5; ++k) {
                int x = tid + k - 1;
                float xv = (x >= 0 && x < 256) ? ps[x] : 0.f;
                s += w1s[c * 5 + k] * xv;
            }
            q1p[r * 1024 + c * 256 + tid] = s;
        }
    }
}

// ---------------- kernel: c1p[c][l][b] = (conv1(data)[c][2l], [2l+1]) ----------------
__global__ __launch_bounds__(64) void k_prep_c1d(const float* __restrict__ dTp,
                                                 const float* __restrict__ w1,
                                                 float2* __restrict__ c1p) {
    int lane = threadIdx.x;
    int bg = blockIdx.x >> 3, ch = blockIdx.x & 7;
    int l0 = ch << 4;
    int nl = (ch == 7) ? 15 : 16;
    int b = (bg << 6) + lane;
    float w1r[20];
#pragma unroll
    for (int i = 0; i < 20; ++i) w1r[i] = w1[i];
    const float* dp = dTp + (size_t)(2 * l0) * 4096 + b;
    float d[6];
#pragma unroll
    for (int i = 0; i < 6; ++i) d[i] = dp[(size_t)i * 4096];
    dp += (size_t)6 * 4096;
    float2* outp = c1p + b;
    for (int li = 0; li < nl; ++li) {
        int l = l0 + li;
#pragma unroll
        for (int c = 0; c < 4; ++c) {
            float s0 = 0.f, s1 = 0.f;
#pragma unroll
            for (int k = 0; k < 5; ++k) {
                s0 += w1r[c * 5 + k] * d[k];
                s1 += w1r[c * 5 + k] * d[k + 1];
            }
            outp[(size_t)(c * 127 + l) * 4096] = make_float2(s0, s1);
        }
        d[0] = d[2]; d[1] = d[3]; d[2] = d[4]; d[3] = d[5];
        d[4] = dp[0];
        d[5] = dp[4096];
        dp += 8192;
    }
}

// ---------------- kernel: B^T cast via LDS tile (+bias rows at k>=8192) ----------------
__global__ __launch_bounds__(256) void k_castB(const float* __restrict__ cw,
                                               const float* __restrict__ cb,
                                               unsigned short* __restrict__ BT) {
    __shared__ unsigned short L[64 * 137];
    int tid = threadIdx.x;
    int kt = blockIdx.x >> 3, ct = blockIdx.x & 7;
    int k0 = kt << 6, c0 = ct << 7;
#pragma unroll
    for (int i = 0; i < 32; ++i) {
        int flat = i * 256 + tid;
        int cl = flat & 127, kl = flat >> 7;
        int cg = c0 + cl;
        int kg = k0 + kl;
        float v = 0.f;
        if (cg < 1000) {
            if (kg < 8192) v = cw[(size_t)kg * 1000 + cg];
            else if (kg < 8224) v = cb[(size_t)(kg - 8192) * 1000 + cg];
        }
        L[kl * 137 + cl] = f2bf_rne(v);
    }
    __syncthreads();
#pragma unroll
    for (int i = 0; i < 4; ++i) {
        int task = i * 256 + tid;
        int kg = task & 7, cl = task >> 3;
        int base = kg * 8 * 137 + cl;
        unsigned x = (unsigned)L[base] | ((unsigned)L[base + 137] << 16);
        unsigned y = (unsigned)L[base + 2 * 137] | ((unsigned)L[base + 3 * 137] << 16);
        unsigned z = (unsigned)L[base + 4 * 137] | ((unsigned)L[base + 5 * 137] << 16);
        unsigned w = (unsigned)L[base + 6 * 137] | ((unsigned)L[base + 7 * 137] << 16);
        uint4 o; o.x = x; o.y = y; o.z = z; o.w = w;
        int cg = c0 + cl;
        size_t byte = (size_t)cg * KROW + (size_t)(kt << 7) + (size_t)((kg ^ (cg & 7)) << 4);
        *(uint4*)((char*)BT + byte) = o;
    }
}

// ---------------- kernel: fc1_w cast -> pre-swizzled ----------------
__global__ __launch_bounds__(256) void k_castW(const float* __restrict__ fc1w,
                                               unsigned short* __restrict__ W1s) {
    int idx = blockIdx.x * 256 + threadIdx.x;
    int col = idx >> 8, k = idx & 255;
    float v = 0.f;
    if (col < 124 && k < 248) {
        int f = (k & 3) * 62 + (k >> 2);
        v = fc1w[f * 124 + col];
    }
    int byte = col * 512 + ((k >> 6) << 7) + ((((k >> 3) & 7) ^ (col & 7)) << 4) + ((k & 7) << 1);
    *(unsigned short*)((char*)W1s + byte) = f2bf_rne(v);
}

// ---------------- conv phase A: FULLY UNROLLED (no rolling window) ----------------
// All pooled() offsets are compile-time relative to per-wave bases; overlapping-window
// reuse is plain CSE of identical-address loads. FIRST guards l=-1 (only wave 0).
template<int CNT, bool FIRST>
__device__ __forceinline__ void conv_phaseA(const float2* __restrict__ cpbs,
                                            const float* __restrict__ q1s,
                                            const float* __restrict__ w2,
                                            const float* __restrict__ b2,
                                            unsigned short* Trow, int j2s) {
    float w2r[80];
#pragma unroll
    for (int i = 0; i < 80; ++i) w2r[i] = w2[i];
    v2f bb[4];
#pragma unroll
    for (int c = 0; c < 4; ++c) { float t = b2[c]; bb[c][0] = t; bb[c][1] = t; }

    // pooled at dl = l - 2*j2s  (compile-time after unroll)
    auto pooled = [&](int c, int dl) -> float {
        float2 v = cpbs[(size_t)c * 127 * 4096 + (size_t)dl * 4096];
        float2 q = *(const float2*)(q1s + c * 256 + 2 * dl);
        return 0.5f * (fmaxf(v.x - q.x, 0.f) + fmaxf(v.y - q.y, 0.f));
    };

#pragma unroll
    for (int jj = 0; jj < CNT; ++jj) {
        float p[4][6];
#pragma unroll
        for (int c = 0; c < 4; ++c)
#pragma unroll
            for (int i = 0; i < 6; ++i) {
                int dl = 2 * jj - 1 + i;
                if (FIRST && jj == 0 && i == 0)
                    p[c][i] = 0.f;
                else
                    p[c][i] = pooled(c, dl);
            }
        v2f u[4];
#pragma unroll
        for (int c = 0; c < 4; ++c) u[c] = bb[c];
#pragma unroll
        for (int c = 0; c < 4; ++c)
#pragma unroll
            for (int ci = 0; ci < 4; ++ci)
#pragma unroll
                for (int k = 0; k < 5; ++k) {
                    v2f pp; pp[0] = p[ci][k]; pp[1] = p[ci][k + 1];
                    u[c] += pp * w2r[(c * 4 + ci) * 5 + k];
                }
        float h0 = 0.5f * (fmaxf(u[0][0], 0.f) + fmaxf(u[0][1], 0.f));
        float h1 = 0.5f * (fmaxf(u[1][0], 0.f) + fmaxf(u[1][1], 0.f));
        float h2v = 0.5f * (fmaxf(u[2][0], 0.f) + fmaxf(u[2][1], 0.f));
        float h3 = 0.5f * (fmaxf(u[3][0], 0.f) + fmaxf(u[3][1], 0.f));
        uint2 vv;
        vv.x = (unsigned)f2bf_rne(h0) | ((unsigned)f2bf_rne(h1) << 16);
        vv.y = (unsigned)f2bf_rne(h2v) | ((unsigned)f2bf_rne(h3) << 16);
        *(uint2*)(Trow + (j2s + jj) * 4) = vv;
    }
}

// ---------------- kernel: conv2 + fc1 + fc2 + tanh fused (4-wave blocks) ----------------
// Block 256 thr (4 waves), 64 samples, 1 rule. grid 2048 = 32 r x 64 bc.
// Phase A fully unrolled per wave (16/16/16/14 j2); phase B per-wave 16-row fc MFMA.
__global__ __launch_bounds__(256)
void k_convfc(const float2* __restrict__ c1p,
              const float* __restrict__ q1p,
              const float* __restrict__ w2,
              const float* __restrict__ b2,
              const char* __restrict__ W1s,
              const float* __restrict__ fc1b,
              const float* __restrict__ fc2w,
              const float* __restrict__ fc2b,
              float* __restrict__ fsiniT) {
    __shared__ unsigned short T[64 * 264];   // 33,792 B

    int tid = threadIdx.x;
    int w = tid >> 6, lane = tid & 63;
    int r  = blockIdx.x >> 6;
    int b0 = (blockIdx.x & 63) << 6;
    int j2s = w << 4;

    // ---- phase A ----
    {
        const float* q1row = q1p + r * 1024;
        const float2* cpb = c1p + b0 + lane;
        const float2* cpbs = cpb + (size_t)(2 * j2s) * 4096;   // dl base
        const float* q1s = q1row + 4 * j2s;
        unsigned short* Trow = T + lane * 264;

        if (w == 0)      conv_phaseA<16, true >(cpbs, q1s, w2, b2, Trow, j2s);
        else if (w == 3) conv_phaseA<14, false>(cpbs, q1s, w2, b2, Trow, j2s);
        else             conv_phaseA<16, false>(cpbs, q1s, w2, b2, Trow, j2s);

        if (w == 3) {   // zero-pad k 248..255
            uint4 z; z.x = z.y = z.z = z.w = 0u;
            *(uint4*)(T + lane * 264 + 248) = z;
        }
    }
    __syncthreads();

    // ---- phase B: fc1 + relu + fc2 + tanh (16-row M-tile per wave) ----
    {
        int row0 = w << 4;   // 0,16,32,48
        int lr = lane & 15, g = lane >> 4, rxor = lr & 7;

        f32x4 acc[8] = {};

        const unsigned short* trow = T + (row0 + lr) * 264;

        auto inrowf = [&](int ks) {
            return ((ks >> 1) << 7) + ((((ks * 4 + g) & 7) ^ rxor) << 4);
        };

#pragma unroll
        for (int ks = 0; ks < 8; ++ks) {
            int koff = ks * 32 + g * 8;
            bf16x8 a0 = *(const bf16x8*)(trow + koff);
            int ir = inrowf(ks);
            bf16x8 bfr[8];
#pragma unroll
            for (int nf = 0; nf < 8; ++nf)
                bfr[nf] = *(const bf16x8*)(W1s + (nf * 16 + lr) * 512 + ir);
#pragma unroll
            for (int nf = 0; nf < 8; ++nf)
                acc[nf] = __builtin_amdgcn_mfma_f32_16x16x32_bf16(a0, bfr[nf], acc[nf], 0, 0, 0);
        }

        float zp[4] = {};
#pragma unroll
        for (int nf = 0; nf < 8; ++nf) {
            int col = nf * 16 + lr;
            float b1v = (col < 124) ? fc1b[col] : 0.f;
            float w2v = (col < 124) ? fc2w[col] : 0.f;
#pragma unroll
            for (int q = 0; q < 4; ++q) {
                float h = fmaxf(acc[nf][q] + b1v, 0.f);
                zp[q] += h * w2v;
            }
        }
#pragma unroll
        for (int off = 1; off < 16; off <<= 1) {
#pragma unroll
            for (int q = 0; q < 4; ++q)
                zp[q] += __shfl_xor(zp[q], off, 64);
        }
        if (lr == 0) {
            float c2 = fc2b[0];
            int sbase = r * 4096 + b0 + row0;
#pragma unroll
            for (int q = 0; q < 4; ++q) {
                int srow = sbase + g * 4 + q;
                fsiniT[srow] = tanhf(zp[q] + c2);
            }
        }
    }
}

// ---------------- kernel: softmax over rules ----------------
__global__ __launch_bounds__(256) void k_softmax(const float* __restrict__ fsiniT,
                                                 float* __restrict__ fsT) {
    int b = blockIdx.x * 256 + threadIdx.x;
    float v[32];
    float m = -1e30f;
#pragma unroll
    for (int r = 0; r < 32; ++r) { v[r] = fsiniT[r * 4096 + b]; m = fmaxf(m, v[r]); }
    float s = 0.f;
#pragma unroll
    for (int r = 0; r < 32; ++r) { v[r] = expf(v[r] - m); s += v[r]; }
    float inv = 1.f / s;
#pragma unroll
    for (int r = 0; r < 32; ++r) fsT[r * 4096 + b] = v[r] * inv;
}

// ---------------- kernel: A[b][k], pre-swizzled; k<8192: fs*data, 8192..8223: fs, rest 0 ----------------
__global__ __launch_bounds__(256) void k_scaleA(const float* __restrict__ data,
                                                const float* __restrict__ fsT,
                                                unsigned short* __restrict__ Asc) {
    int g = blockIdx.x * 256 + threadIdx.x;
    int b = g / 1040, kg = g - b * 1040;
    uint4 o;
    unsigned* op = (unsigned*)&o;
    if (kg < 1024) {
        int r = kg >> 5, f0 = (kg & 31) << 3;
        float fs = fsT[r * 4096 + b];
        const float4* dp = (const float4*)(data + b * 256 + f0);
        float4 v0 = dp[0], v1 = dp[1];
        float vals[8] = {v0.x, v0.y, v0.z, v0.w, v1.x, v1.y, v1.z, v1.w};
#pragma unroll
        for (int i = 0; i < 4; ++i) {
            unsigned lo = f2bf_rne(vals[2 * i] * fs);
            unsigned hi = f2bf_rne(vals[2 * i + 1] * fs);
            op[i] = lo | (hi << 16);
        }
    } else {
        int base = (kg - 1024) << 3;
        op[0] = op[1] = op[2] = op[3] = 0u;
        if (base < 32) {
#pragma unroll
            for (int i = 0; i < 4; ++i) {
                unsigned lo = f2bf_rne(fsT[(base + 2 * i) * 4096 + b]);
                unsigned hi = f2bf_rne(fsT[(base + 2 * i + 1) * 4096 + b]);
                op[i] = lo | (hi << 16);
            }
        }
    }
    size_t byte = (size_t)b * KROW + (size_t)((kg & ~7) << 4) + (size_t)(((kg & 7) ^ (b & 7)) << 4);
    *(uint4*)((char*)Asc + byte) = o;
}

// ---------------- kernel: GEMM [4096 x KP] x [KP x 1024], K-split 2, bias folded in ----------------
__global__ __launch_bounds__(512) void k_gemm(const unsigned short* __restrict__ Asc,
                                              const unsigned short* __restrict__ BT,
                                              float* __restrict__ out,
                                              _Float16* __restrict__ part1) {
    __shared__ unsigned short As[2][8192];
    __shared__ unsigned short Bs[2][8192];
    int tid = threadIdx.x, lane = tid & 63, w = tid >> 6;
    int wm = w >> 2, wn = w & 3;
    int bid = blockIdx.x;
    int xcd = bid & 7, idx = bid >> 3;
    int mt = (xcd << 2) | (idx >> 4);
    int nt = (idx >> 1) & 7;
    int ks = idx & 1;
    int row0 = mt << 7, col0 = nt << 7;

    f32x4 acc[4][2] = {};

    const char* Ab = (const char*)Asc + (size_t)ks * (KP);
    const char* Bb = (const char*)BT + (size_t)ks * (KP);
    int flat0 = tid * 16, flat1 = tid * 16 + 8192;
    int rowl0 = flat0 >> 7, colB0 = flat0 & 127;
    int rowl1 = flat1 >> 7, colB1 = flat1 & 127;
    const char* aSrc0 = Ab + (size_t)(row0 + rowl0) * KROW + colB0;
    const char* aSrc1 = Ab + (size_t)(row0 + rowl1) * KROW + colB1;
    const char* bSrc0 = Bb + (size_t)(col0 + rowl0) * KROW + colB0;
    const char* bSrc1 = Bb + (size_t)(col0 + rowl1) * KROW + colB1;

    auto stage = [&](int buf, int kt) {
        int off = kt << 7;
        gload_lds16(aSrc0 + off, (char*)&As[buf][0] + flat0);
        gload_lds16(aSrc1 + off, (char*)&As[buf][0] + flat1);
        gload_lds16(bSrc0 + off, (char*)&Bs[buf][0] + flat0);
        gload_lds16(bSrc1 + off, (char*)&Bs[buf][0] + flat1);
    };

    auto compute = [&](int buf) {
        const char* Asb = (const char*)&As[buf][0];
        const char* Bsb = (const char*)&Bs[buf][0];
#pragma unroll
        for (int s = 0; s < 2; ++s) {
            bf16x8 af[4], bfv[2];
            int colByte = ((s << 5) + ((lane >> 4) << 3)) << 1;
#pragma unroll
            for (int mi = 0; mi < 4; ++mi) {
                int rowA = (wm << 6) + (mi << 4) + (lane & 15);
                int byte = (rowA << 7) + colByte;
                af[mi] = *(const bf16x8*)(Asb + (byte ^ ((rowA & 7) << 4)));
            }
#pragma unroll
            for (int ni = 0; ni < 2; ++ni) {
                int rowB = (wn << 5) + (ni << 4) + (lane & 15);
                int byte = (rowB << 7) + colByte;
                bfv[ni] = *(const bf16x8*)(Bsb + (byte ^ ((rowB & 7) << 4)));
            }
#pragma unroll
            for (int mi = 0; mi < 4; ++mi)
#pragma unroll
                for (int ni = 0; ni < 2; ++ni)
                    acc[mi][ni] = __builtin_amdgcn_mfma_f32_16x16x32_bf16(af[mi], bfv[ni], acc[mi][ni], 0, 0, 0);
        }
    };

    stage(0, 0);
    asm volatile("s_waitcnt vmcnt(0)" ::: "memory");
    __syncthreads();
#pragma unroll 1
    for (int kt = 0; kt < 64; ++kt) {
        stage((kt + 1) & 1, kt + 1);
        compute(kt & 1);
        asm volatile("s_waitcnt vmcnt(0)" ::: "memory");
        __syncthreads();
    }
    compute(0);

    int cA = col0 + (wn << 5) + (lane & 15);
    int cB2 = cA + 16;
    int rbase = row0 + (wm << 6) + ((lane >> 4) << 2);

    if (ks == 0) {
#pragma unroll
        for (int mi = 0; mi < 4; ++mi)
#pragma unroll
            for (int q = 0; q < 4; ++q) {
                int row = rbase + mi * 16 + q;
                if (cA < 1000) out[row * 1000 + cA] = acc[mi][0][q];
                if (cB2 < 1000) out[row * 1000 + cB2] = acc[mi][1][q];
            }
    } else {
#pragma unroll
        for (int mi = 0; mi < 4; ++mi)
#pragma unroll
            for (int q = 0; q < 4; ++q) {
                int row = rbase + mi * 16 + q;
                if (cA < 1000) part1[row * 1000 + cA] = (_Float16)acc[mi][0][q];
                if (cB2 < 1000) part1[row * 1000 + cB2] = (_Float16)acc[mi][1][q];
            }
    }
}

// ---------------- kernel: out += part1 ----------------
__global__ __launch_bounds__(256) void k_reduce(float* __restrict__ out,
                                                const _Float16* __restrict__ p1) {
    int i = (blockIdx.x * 256 + threadIdx.x) * 4;
    float4 o = *(float4*)(out + i);
    o.x += (float)p1[i];
    o.y += (float)p1[i + 1];
    o.z += (float)p1[i + 2];
    o.w += (float)p1[i + 3];
    *(float4*)(out + i) = o;
}

// ---------------- launch ----------------
extern "C" void kernel_launch(void* const* d_in, const int* in_sizes, int n_in,
                              void* d_out, int out_size, void* d_ws, size_t ws_size,
                              hipStream_t stream) {
    const float* data  = (const float*)d_in[0];
    const float* proto = (const float*)d_in[1];
    const float* w1    = (const float*)d_in[2];
    const float* b1    = (const float*)d_in[3];
    const float* w2    = (const float*)d_in[4];
    const float* b2    = (const float*)d_in[5];
    const float* fc1w  = (const float*)d_in[6];
    const float* fc1b  = (const float*)d_in[7];
    const float* fc2w  = (const float*)d_in[8];
    const float* fc2b  = (const float*)d_in[9];
    const float* cw    = (const float*)d_in[10];
    const float* cbias = (const float*)d_in[11];
    float* out = (float*)d_out;
    char* ws = (char*)d_ws;

    float* dTp             = (float*)(ws + OFF_DT);
    float* q1p             = (float*)(ws + OFF_Q1);
    float2* c1p            = (float2*)(ws + OFF_C1P);
    unsigned short* BT     = (unsigned short*)(ws + OFF_BT);
    unsigned short* W1s    = (unsigned short*)(ws + OFF_W1S);
    float* fsiniT          = (float*)(ws + OFF_FSI);
    float* fsT             = (float*)(ws + OFF_FS);
    unsigned short* Asc    = (unsigned short*)(ws + OFF_ASC);
    _Float16* part1        = (_Float16*)(ws + OFF_P1);

    hipLaunchKernelGGL(k_transpose, dim3(256), dim3(256), 0, stream, data, dTp);
    hipLaunchKernelGGL(k_zrows, dim3(16), dim3(256), 0, stream, dTp);
    hipLaunchKernelGGL(k_prep_proto, dim3(32), dim3(256), 0, stream, proto, w1, b1, q1p);
    hipLaunchKernelGGL(k_prep_c1d, dim3(512), dim3(64), 0, stream, dTp, w1, c1p);
    hipLaunchKernelGGL(k_castW, dim3(128), dim3(256), 0, stream, fc1w, W1s);
    hipLaunchKernelGGL(k_convfc, dim3(2048), dim3(256), 0, stream,
                       c1p, q1p, w2, b2, (const char*)W1s, fc1b, fc2w, fc2b, fsiniT);
    // castB AFTER convfc: BT region aliases c1p
    hipLaunchKernelGGL(k_castB, dim3(1040), dim3(256), 0, stream, cw, cbias, BT);
    hipLaunchKernelGGL(k_softmax, dim3(16), dim3(256), 0, stream, fsiniT, fsT);
    hipLaunchKernelGGL(k_scaleA, dim3(16640), dim3(256), 0, stream, data, fsT, Asc);
    hipLaunchKernelGGL(k_gemm, dim3(512), dim3(512), 0, stream, Asc, BT, out, part1);
    hipLaunchKernelGGL(k_reduce, dim3(4000), dim3(256), 0, stream, out, part1);
}

// Round 19
// 237.025 us; speedup vs baseline: 1.6540x; 1.6540x over previous
//
#include <hip/hip_runtime.h>
#include <hip/hip_bf16.h>

// ---------------- types / helpers ----------------
using bf16x8 = __attribute__((ext_vector_type(8))) short;
using f32x4  = __attribute__((ext_vector_type(4))) float;
using v2f    = __attribute__((ext_vector_type(2))) float;

__device__ __forceinline__ unsigned short f2bf_rne(float x) {
    unsigned u = __float_as_uint(x);
    u += 0x7fffu + ((u >> 16) & 1u);
    return (unsigned short)(u >> 16);
}

__device__ __forceinline__ void gload_lds16(const void* g, void* l) {
    __builtin_amdgcn_global_load_lds(
        (const __attribute__((address_space(1))) unsigned int*)g,
        (__attribute__((address_space(3))) unsigned int*)l, 16, 0, 0);
}

// K geometry: 8192 data k + 32 bias rows (fs x consq_b) + zero-pad -> 8320 = 2 x 65 x 64
constexpr int KP = 8320;
constexpr int KROW = KP * 2;

// ---------------- workspace layout (bytes) ----------------
constexpr size_t OFF_DT  = 0;                                  // [260][4096] f32 padded dataT
constexpr size_t OFF_Q1  = OFF_DT  + (size_t)260 * 4096 * 4;   // [32][4][256] f32 q1
constexpr size_t OFF_BT  = OFF_Q1  + (size_t)32 * 1024 * 4;    // [1024][KP] bf16 pre-swizzled B^T (+bias rows)
constexpr size_t OFF_C1P = OFF_BT;                             // [4][127][4096] u32 bf16-pair (aliases BT)
constexpr size_t OFF_W1S = OFF_BT  + (size_t)1024 * KP * 2;    // [128][256] bf16 pre-swizzled fc1_w
constexpr size_t OFF_FSI = OFF_W1S + (size_t)128 * 256 * 2;    // [131072] f32 fs_ini
constexpr size_t OFF_FS  = OFF_FSI + (size_t)32 * 4096 * 4;    // [32][4096] f32 fs^T
constexpr size_t OFF_ASC = OFF_FS  + (size_t)32 * 4096 * 4;    // [4096][KP] bf16 A
constexpr size_t OFF_P1  = OFF_ASC + (size_t)4096 * KP * 2;    // [4096][1000] f16 K-split partial
// total = ~98.9 MB

// ---------------- kernel: transpose data [4096][256] -> dTp rows 1..256 ----------------
__global__ __launch_bounds__(256) void k_transpose(const float* __restrict__ data,
                                                   float* __restrict__ dTp) {
    __shared__ float tile[64][65];
    int bx = blockIdx.x & 63;
    int fx = blockIdx.x >> 6;
    int tx = threadIdx.x & 63, ty4 = threadIdx.x >> 6;
#pragma unroll
    for (int i = 0; i < 16; ++i) {
        int ty = ty4 * 16 + i;
        tile[ty][tx] = data[(bx * 64 + ty) * 256 + fx * 64 + tx];
    }
    __syncthreads();
#pragma unroll
    for (int i = 0; i < 16; ++i) {
        int ty = ty4 * 16 + i;
        dTp[(size_t)(fx * 64 + ty + 1) * 4096 + bx * 64 + tx] = tile[tx][ty];
    }
}

__global__ __launch_bounds__(256) void k_zrows(float* __restrict__ dTp) {
    int i = blockIdx.x * 256 + threadIdx.x;
    dTp[i] = 0.f;
    dTp[(size_t)257 * 4096 + i] = 0.f;
}

// ---------------- kernel: q1 = conv1(proto) - b1 ----------------
__global__ __launch_bounds__(256) void k_prep_proto(const float* __restrict__ proto,
                                                    const float* __restrict__ w1,
                                                    const float* __restrict__ b1,
                                                    float* __restrict__ q1p) {
    __shared__ float ps[256];
    __shared__ float w1s[20];
    int r = blockIdx.x, tid = threadIdx.x;
    ps[tid] = proto[r * 256 + tid];
    if (tid < 20) w1s[tid] = w1[tid];
    __syncthreads();
    if (tid < 254) {
#pragma unroll
        for (int c = 0; c < 4; ++c) {
            float s = -b1[c];
#pragma unroll
            for (int k = 0; k < 5; ++k) {
                int x = tid + k - 1;
                float xv = (x >= 0 && x < 256) ? ps[x] : 0.f;
                s += w1s[c * 5 + k] * xv;
            }
            q1p[r * 1024 + c * 256 + tid] = s;
        }
    }
}

// ---------------- kernel: c1p[c][l][b] = packed bf16 (conv1[c][2l], conv1[c][2l+1]) ----------------
__global__ __launch_bounds__(64) void k_prep_c1d(const float* __restrict__ dTp,
                                                 const float* __restrict__ w1,
                                                 unsigned* __restrict__ c1p) {
    int lane = threadIdx.x;
    int bg = blockIdx.x >> 3, ch = blockIdx.x & 7;
    int l0 = ch << 4;
    int nl = (ch == 7) ? 15 : 16;
    int b = (bg << 6) + lane;
    float w1r[20];
#pragma unroll
    for (int i = 0; i < 20; ++i) w1r[i] = w1[i];
    const float* dp = dTp + (size_t)(2 * l0) * 4096 + b;
    float d[6];
#pragma unroll
    for (int i = 0; i < 6; ++i) d[i] = dp[(size_t)i * 4096];
    dp += (size_t)6 * 4096;
    unsigned* outp = c1p + b;
    for (int li = 0; li < nl; ++li) {
        int l = l0 + li;
#pragma unroll
        for (int c = 0; c < 4; ++c) {
            float s0 = 0.f, s1 = 0.f;
#pragma unroll
            for (int k = 0; k < 5; ++k) {
                s0 += w1r[c * 5 + k] * d[k];
                s1 += w1r[c * 5 + k] * d[k + 1];
            }
            outp[(size_t)(c * 127 + l) * 4096] =
                (unsigned)f2bf_rne(s0) | ((unsigned)f2bf_rne(s1) << 16);
        }
        d[0] = d[2]; d[1] = d[3]; d[2] = d[4]; d[3] = d[5];
        d[4] = dp[0];
        d[5] = dp[4096];
        dp += 8192;
    }
}

// ---------------- kernel: B^T cast via LDS tile (+bias rows at k>=8192) ----------------
__global__ __launch_bounds__(256) void k_castB(const float* __restrict__ cw,
                                               const float* __restrict__ cb,
                                               unsigned short* __restrict__ BT) {
    __shared__ unsigned short L[64 * 137];
    int tid = threadIdx.x;
    int kt = blockIdx.x >> 3, ct = blockIdx.x & 7;
    int k0 = kt << 6, c0 = ct << 7;
#pragma unroll
    for (int i = 0; i < 32; ++i) {
        int flat = i * 256 + tid;
        int cl = flat & 127, kl = flat >> 7;
        int cg = c0 + cl;
        int kg = k0 + kl;
        float v = 0.f;
        if (cg < 1000) {
            if (kg < 8192) v = cw[(size_t)kg * 1000 + cg];
            else if (kg < 8224) v = cb[(size_t)(kg - 8192) * 1000 + cg];
        }
        L[kl * 137 + cl] = f2bf_rne(v);
    }
    __syncthreads();
#pragma unroll
    for (int i = 0; i < 4; ++i) {
        int task = i * 256 + tid;
        int kg = task & 7, cl = task >> 3;
        int base = kg * 8 * 137 + cl;
        unsigned x = (unsigned)L[base] | ((unsigned)L[base + 137] << 16);
        unsigned y = (unsigned)L[base + 2 * 137] | ((unsigned)L[base + 3 * 137] << 16);
        unsigned z = (unsigned)L[base + 4 * 137] | ((unsigned)L[base + 5 * 137] << 16);
        unsigned w = (unsigned)L[base + 6 * 137] | ((unsigned)L[base + 7 * 137] << 16);
        uint4 o; o.x = x; o.y = y; o.z = z; o.w = w;
        int cg = c0 + cl;
        size_t byte = (size_t)cg * KROW + (size_t)(kt << 7) + (size_t)((kg ^ (cg & 7)) << 4);
        *(uint4*)((char*)BT + byte) = o;
    }
}

// ---------------- kernel: fc1_w cast -> pre-swizzled ----------------
__global__ __launch_bounds__(256) void k_castW(const float* __restrict__ fc1w,
                                               unsigned short* __restrict__ W1s) {
    int idx = blockIdx.x * 256 + threadIdx.x;
    int col = idx >> 8, k = idx & 255;
    float v = 0.f;
    if (col < 124 && k < 248) {
        int f = (k & 3) * 62 + (k >> 2);
        v = fc1w[f * 124 + col];
    }
    int byte = col * 512 + ((k >> 6) << 7) + ((((k >> 3) & 7) ^ (col & 7)) << 4) + ((k & 7) << 1);
    *(unsigned short*)((char*)W1s + byte) = f2bf_rne(v);
}

// ---------------- kernel: conv2 + fc1 + fc2 + tanh fused (4-wave blocks) ----------------
// Block 256 thr (4 waves), 64 samples, 1 rule. grid 2048 = 32 r x 64 bc.
// r17 structure (244.7 us best) with ONE change: c1p is packed bf16 pairs -> pooled
// load traffic halved (520 -> 260 MB LLC), c1p shrinks 16.6 -> 8.3 MB.
__global__ __launch_bounds__(256)
void k_convfc(const unsigned* __restrict__ c1p,
              const float* __restrict__ q1p,
              const float* __restrict__ w2,
              const float* __restrict__ b2,
              const char* __restrict__ W1s,
              const float* __restrict__ fc1b,
              const float* __restrict__ fc2w,
              const float* __restrict__ fc2b,
              float* __restrict__ fsiniT) {
    __shared__ unsigned short T[64 * 264];   // 33,792 B

    int tid = threadIdx.x;
    int w = tid >> 6, lane = tid & 63;
    int r  = blockIdx.x >> 6;
    int b0 = (blockIdx.x & 63) << 6;
    int j2s = w << 4;

    // ---- phase A: conv2 (rolling window; T-store natural) ----
    {
        float w2r[80];
#pragma unroll
        for (int i = 0; i < 80; ++i) w2r[i] = w2[i];
        v2f bb[4];
#pragma unroll
        for (int c = 0; c < 4; ++c) { float t = b2[c]; bb[c][0] = t; bb[c][1] = t; }

        const float* q1row = q1p + r * 1024;
        const unsigned* cpb = c1p + b0 + lane;

        auto pooled = [&](int c, int l) -> float {
            unsigned u = cpb[(size_t)(c * 127 + l) * 4096];
            float2 q = *(const float2*)(q1row + c * 256 + 2 * l);
            float vx = __uint_as_float(u << 16);
            float vy = __uint_as_float(u & 0xffff0000u);
            return 0.5f * (fmaxf(vx - q.x, 0.f) + fmaxf(vy - q.y, 0.f));
        };

        v2f P[4][5];
#pragma unroll
        for (int c = 0; c < 4; ++c) {
            float pv[6];
#pragma unroll
            for (int idx = 0; idx < 6; ++idx) {
                int l = 2 * j2s - 1 + idx;
                pv[idx] = (l < 0) ? 0.f : pooled(c, l);
            }
#pragma unroll
            for (int k = 0; k < 5; ++k) { P[c][k][0] = pv[k]; P[c][k][1] = pv[k + 1]; }
        }

        int cnt = (w == 3) ? 14 : 16;
        int j2 = j2s;
#pragma unroll 1
        for (int jj = 0; jj < cnt; ++jj) {
            v2f u[4];
#pragma unroll
            for (int c = 0; c < 4; ++c) u[c] = bb[c];
#pragma unroll
            for (int c = 0; c < 4; ++c)
#pragma unroll
                for (int ci = 0; ci < 4; ++ci)
#pragma unroll
                    for (int k = 0; k < 5; ++k)
                        u[c] += P[ci][k] * w2r[(c * 4 + ci) * 5 + k];
            {
                float h0 = 0.5f * (fmaxf(u[0][0], 0.f) + fmaxf(u[0][1], 0.f));
                float h1 = 0.5f * (fmaxf(u[1][0], 0.f) + fmaxf(u[1][1], 0.f));
                float h2v = 0.5f * (fmaxf(u[2][0], 0.f) + fmaxf(u[2][1], 0.f));
                float h3 = 0.5f * (fmaxf(u[3][0], 0.f) + fmaxf(u[3][1], 0.f));
                uint2 vv;
                vv.x = (unsigned)f2bf_rne(h0) | ((unsigned)f2bf_rne(h1) << 16);
                vv.y = (unsigned)f2bf_rne(h2v) | ((unsigned)f2bf_rne(h3) << 16);
                *(uint2*)(T + lane * 264 + j2 * 4) = vv;
            }
            if (jj < cnt - 1) {
#pragma unroll
                for (int c = 0; c < 4; ++c) {
                    float n0 = pooled(c, 2 * j2 + 5);
                    float n1 = pooled(c, 2 * j2 + 6);
                    v2f p4v = P[c][4];
                    P[c][0] = P[c][2]; P[c][1] = P[c][3]; P[c][2] = p4v;
                    v2f t3; t3[0] = p4v[1]; t3[1] = n0;
                    v2f t4; t4[0] = n0;     t4[1] = n1;
                    P[c][3] = t3; P[c][4] = t4;
                }
            }
            ++j2;
        }
        if (w == 3) {   // zero-pad k 248..255
            uint4 z; z.x = z.y = z.z = z.w = 0u;
            *(uint4*)(T + lane * 264 + 248) = z;
        }
    }
    __syncthreads();

    // ---- phase B: fc1 + relu + fc2 + tanh (16-row M-tile per wave) ----
    {
        int row0 = w << 4;   // 0,16,32,48
        int lr = lane & 15, g = lane >> 4, rxor = lr & 7;

        f32x4 acc[8] = {};

        const unsigned short* trow = T + (row0 + lr) * 264;

        auto inrowf = [&](int ks) {
            return ((ks >> 1) << 7) + ((((ks * 4 + g) & 7) ^ rxor) << 4);
        };

#pragma unroll
        for (int ks = 0; ks < 8; ++ks) {
            int koff = ks * 32 + g * 8;
            bf16x8 a0 = *(const bf16x8*)(trow + koff);
            int ir = inrowf(ks);
            bf16x8 bfr[8];
#pragma unroll
            for (int nf = 0; nf < 8; ++nf)
                bfr[nf] = *(const bf16x8*)(W1s + (nf * 16 + lr) * 512 + ir);
#pragma unroll
            for (int nf = 0; nf < 8; ++nf)
                acc[nf] = __builtin_amdgcn_mfma_f32_16x16x32_bf16(a0, bfr[nf], acc[nf], 0, 0, 0);
        }

        float zp[4] = {};
#pragma unroll
        for (int nf = 0; nf < 8; ++nf) {
            int col = nf * 16 + lr;
            float b1v = (col < 124) ? fc1b[col] : 0.f;
            float w2v = (col < 124) ? fc2w[col] : 0.f;
#pragma unroll
            for (int q = 0; q < 4; ++q) {
                float h = fmaxf(acc[nf][q] + b1v, 0.f);
                zp[q] += h * w2v;
            }
        }
#pragma unroll
        for (int off = 1; off < 16; off <<= 1) {
#pragma unroll
            for (int q = 0; q < 4; ++q)
                zp[q] += __shfl_xor(zp[q], off, 64);
        }
        if (lr == 0) {
            float c2 = fc2b[0];
            int sbase = r * 4096 + b0 + row0;
#pragma unroll
            for (int q = 0; q < 4; ++q) {
                int srow = sbase + g * 4 + q;
                fsiniT[srow] = tanhf(zp[q] + c2);
            }
        }
    }
}

// ---------------- kernel: softmax over rules ----------------
__global__ __launch_bounds__(256) void k_softmax(const float* __restrict__ fsiniT,
                                                 float* __restrict__ fsT) {
    int b = blockIdx.x * 256 + threadIdx.x;
    float v[32];
    float m = -1e30f;
#pragma unroll
    for (int r = 0; r < 32; ++r) { v[r] = fsiniT[r * 4096 + b]; m = fmaxf(m, v[r]); }
    float s = 0.f;
#pragma unroll
    for (int r = 0; r < 32; ++r) { v[r] = expf(v[r] - m); s += v[r]; }
    float inv = 1.f / s;
#pragma unroll
    for (int r = 0; r < 32; ++r) fsT[r * 4096 + b] = v[r] * inv;
}

// ---------------- kernel: A[b][k], pre-swizzled; k<8192: fs*data, 8192..8223: fs, rest 0 ----------------
__global__ __launch_bounds__(256) void k_scaleA(const float* __restrict__ data,
                                                const float* __restrict__ fsT,
                                                unsigned short* __restrict__ Asc) {
    int g = blockIdx.x * 256 + threadIdx.x;
    int b = g / 1040, kg = g - b * 1040;
    uint4 o;
    unsigned* op = (unsigned*)&o;
    if (kg < 1024) {
        int r = kg >> 5, f0 = (kg & 31) << 3;
        float fs = fsT[r * 4096 + b];
        const float4* dp = (const float4*)(data + b * 256 + f0);
        float4 v0 = dp[0], v1 = dp[1];
        float vals[8] = {v0.x, v0.y, v0.z, v0.w, v1.x, v1.y, v1.z, v1.w};
#pragma unroll
        for (int i = 0; i < 4; ++i) {
            unsigned lo = f2bf_rne(vals[2 * i] * fs);
            unsigned hi = f2bf_rne(vals[2 * i + 1] * fs);
            op[i] = lo | (hi << 16);
        }
    } else {
        int base = (kg - 1024) << 3;
        op[0] = op[1] = op[2] = op[3] = 0u;
        if (base < 32) {
#pragma unroll
            for (int i = 0; i < 4; ++i) {
                unsigned lo = f2bf_rne(fsT[(base + 2 * i) * 4096 + b]);
                unsigned hi = f2bf_rne(fsT[(base + 2 * i + 1) * 4096 + b]);
                op[i] = lo | (hi << 16);
            }
        }
    }
    size_t byte = (size_t)b * KROW + (size_t)((kg & ~7) << 4) + (size_t)(((kg & 7) ^ (b & 7)) << 4);
    *(uint4*)((char*)Asc + byte) = o;
}

// ---------------- kernel: GEMM [4096 x KP] x [KP x 1024], K-split 2, bias folded in ----------------
__global__ __launch_bounds__(512) void k_gemm(const unsigned short* __restrict__ Asc,
                                              const unsigned short* __restrict__ BT,
                                              float* __restrict__ out,
                                              _Float16* __restrict__ part1) {
    __shared__ unsigned short As[2][8192];
    __shared__ unsigned short Bs[2][8192];
    int tid = threadIdx.x, lane = tid & 63, w = tid >> 6;
    int wm = w >> 2, wn = w & 3;
    int bid = blockIdx.x;
    int xcd = bid & 7, idx = bid >> 3;
    int mt = (xcd << 2) | (idx >> 4);
    int nt = (idx >> 1) & 7;
    int ks = idx & 1;
    int row0 = mt << 7, col0 = nt << 7;

    f32x4 acc[4][2] = {};

    const char* Ab = (const char*)Asc + (size_t)ks * (KP);
    const char* Bb = (const char*)BT + (size_t)ks * (KP);
    int flat0 = tid * 16, flat1 = tid * 16 + 8192;
    int rowl0 = flat0 >> 7, colB0 = flat0 & 127;
    int rowl1 = flat1 >> 7, colB1 = flat1 & 127;
    const char* aSrc0 = Ab + (size_t)(row0 + rowl0) * KROW + colB0;
    const char* aSrc1 = Ab + (size_t)(row0 + rowl1) * KROW + colB1;
    const char* bSrc0 = Bb + (size_t)(col0 + rowl0) * KROW + colB0;
    const char* bSrc1 = Bb + (size_t)(col0 + rowl1) * KROW + colB1;

    auto stage = [&](int buf, int kt) {
        int off = kt << 7;
        gload_lds16(aSrc0 + off, (char*)&As[buf][0] + flat0);
        gload_lds16(aSrc1 + off, (char*)&As[buf][0] + flat1);
        gload_lds16(bSrc0 + off, (char*)&Bs[buf][0] + flat0);
        gload_lds16(bSrc1 + off, (char*)&Bs[buf][0] + flat1);
    };

    auto compute = [&](int buf) {
        const char* Asb = (const char*)&As[buf][0];
        const char* Bsb = (const char*)&Bs[buf][0];
#pragma unroll
        for (int s = 0; s < 2; ++s) {
            bf16x8 af[4], bfv[2];
            int colByte = ((s << 5) + ((lane >> 4) << 3)) << 1;
#pragma unroll
            for (int mi = 0; mi < 4; ++mi) {
                int rowA = (wm << 6) + (mi << 4) + (lane & 15);
                int byte = (rowA << 7) + colByte;
                af[mi] = *(const bf16x8*)(Asb + (byte ^ ((rowA & 7) << 4)));
            }
#pragma unroll
            for (int ni = 0; ni < 2; ++ni) {
                int rowB = (wn << 5) + (ni << 4) + (lane & 15);
                int byte = (rowB << 7) + colByte;
                bfv[ni] = *(const bf16x8*)(Bsb + (byte ^ ((rowB & 7) << 4)));
            }
#pragma unroll
            for (int mi = 0; mi < 4; ++mi)
#pragma unroll
                for (int ni = 0; ni < 2; ++ni)
                    acc[mi][ni] = __builtin_amdgcn_mfma_f32_16x16x32_bf16(af[mi], bfv[ni], acc[mi][ni], 0, 0, 0);
        }
    };

    stage(0, 0);
    asm volatile("s_waitcnt vmcnt(0)" ::: "memory");
    __syncthreads();
#pragma unroll 1
    for (int kt = 0; kt < 64; ++kt) {
        stage((kt + 1) & 1, kt + 1);
        compute(kt & 1);
        asm volatile("s_waitcnt vmcnt(0)" ::: "memory");
        __syncthreads();
    }
    compute(0);

    int cA = col0 + (wn << 5) + (lane & 15);
    int cB2 = cA + 16;
    int rbase = row0 + (wm << 6) + ((lane >> 4) << 2);

    if (ks == 0) {
#pragma unroll
        for (int mi = 0; mi < 4; ++mi)
#pragma unroll
            for (int q = 0; q < 4; ++q) {
                int row = rbase + mi * 16 + q;
                if (cA < 1000) out[row * 1000 + cA] = acc[mi][0][q];
                if (cB2 < 1000) out[row * 1000 + cB2] = acc[mi][1][q];
            }
    } else {
#pragma unroll
        for (int mi = 0; mi < 4; ++mi)
#pragma unroll
            for (int q = 0; q < 4; ++q) {
                int row = rbase + mi * 16 + q;
                if (cA < 1000) part1[row * 1000 + cA] = (_Float16)acc[mi][0][q];
                if (cB2 < 1000) part1[row * 1000 + cB2] = (_Float16)acc[mi][1][q];
            }
    }
}

// ---------------- kernel: out += part1 ----------------
__global__ __launch_bounds__(256) void k_reduce(float* __restrict__ out,
                                                const _Float16* __restrict__ p1) {
    int i = (blockIdx.x * 256 + threadIdx.x) * 4;
    float4 o = *(float4*)(out + i);
    o.x += (float)p1[i];
    o.y += (float)p1[i + 1];
    o.z += (float)p1[i + 2];
    o.w += (float)p1[i + 3];
    *(float4*)(out + i) = o;
}

// ---------------- launch ----------------
extern "C" void kernel_launch(void* const* d_in, const int* in_sizes, int n_in,
                              void* d_out, int out_size, void* d_ws, size_t ws_size,
                              hipStream_t stream) {
    const float* data  = (const float*)d_in[0];
    const float* proto = (const float*)d_in[1];
    const float* w1    = (const float*)d_in[2];
    const float* b1    = (const float*)d_in[3];
    const float* w2    = (const float*)d_in[4];
    const float* b2    = (const float*)d_in[5];
    const float* fc1w  = (const float*)d_in[6];
    const float* fc1b  = (const float*)d_in[7];
    const float* fc2w  = (const float*)d_in[8];
    const float* fc2b  = (const float*)d_in[9];
    const float* cw    = (const float*)d_in[10];
    const float* cbias = (const float*)d_in[11];
    float* out = (float*)d_out;
    char* ws = (char*)d_ws;

    float* dTp             = (float*)(ws + OFF_DT);
    float* q1p             = (float*)(ws + OFF_Q1);
    unsigned* c1p          = (unsigned*)(ws + OFF_C1P);
    unsigned short* BT     = (unsigned short*)(ws + OFF_BT);
    unsigned short* W1s    = (unsigned short*)(ws + OFF_W1S);
    float* fsiniT          = (float*)(ws + OFF_FSI);
    float* fsT             = (float*)(ws + OFF_FS);
    unsigned short* Asc    = (unsigned short*)(ws + OFF_ASC);
    _Float16* part1        = (_Float16*)(ws + OFF_P1);

    hipLaunchKernelGGL(k_transpose, dim3(256), dim3(256), 0, stream, data, dTp);
    hipLaunchKernelGGL(k_zrows, dim3(16), dim3(256), 0, stream, dTp);
    hipLaunchKernelGGL(k_prep_proto, dim3(32), dim3(256), 0, stream, proto, w1, b1, q1p);
    hipLaunchKernelGGL(k_prep_c1d, dim3(512), dim3(64), 0, stream, dTp, w1, c1p);
    hipLaunchKernelGGL(k_castW, dim3(128), dim3(256), 0, stream, fc1w, W1s);
    hipLaunchKernelGGL(k_convfc, dim3(2048), dim3(256), 0, stream,
                       c1p, q1p, w2, b2, (const char*)W1s, fc1b, fc2w, fc2b, fsiniT);
    // castB AFTER convfc: BT region aliases c1p
    hipLaunchKernelGGL(k_castB, dim3(1040), dim3(256), 0, stream, cw, cbias, BT);
    hipLaunchKernelGGL(k_softmax, dim3(16), dim3(256), 0, stream, fsiniT, fsT);
    hipLaunchKernelGGL(k_scaleA, dim3(16640), dim3(256), 0, stream, data, fsT, Asc);
    hipLaunchKernelGGL(k_gemm, dim3(512), dim3(512), 0, stream, Asc, BT, out, part1);
    hipLaunchKernelGGL(k_reduce, dim3(4000), dim3(256), 0, stream, out, part1);
}

// Round 20
// 234.305 us; speedup vs baseline: 1.6732x; 1.0116x over previous
//
#include <hip/hip_runtime.h>
#include <hip/hip_bf16.h>

// ---------------- types / helpers ----------------
using bf16x8 = __attribute__((ext_vector_type(8))) short;
using f32x4  = __attribute__((ext_vector_type(4))) float;
using v2f    = __attribute__((ext_vector_type(2))) float;

__device__ __forceinline__ unsigned short f2bf_rne(float x) {
    unsigned u = __float_as_uint(x);
    u += 0x7fffu + ((u >> 16) & 1u);
    return (unsigned short)(u >> 16);
}

__device__ __forceinline__ void gload_lds16(const void* g, void* l) {
    __builtin_amdgcn_global_load_lds(
        (const __attribute__((address_space(1))) unsigned int*)g,
        (__attribute__((address_space(3))) unsigned int*)l, 16, 0, 0);
}

// K geometry: 8192 data k + 32 bias rows (fs x consq_b) + zero-pad -> 8320 = 2 x 65 x 64
constexpr int KP = 8320;
constexpr int KROW = KP * 2;

// ---------------- workspace layout (bytes) ----------------
constexpr size_t OFF_DT  = 0;                                  // [260][4096] f32 padded dataT
constexpr size_t OFF_Q1  = OFF_DT  + (size_t)260 * 4096 * 4;   // [32][4][256] f32 q1
constexpr size_t OFF_BT  = OFF_Q1  + (size_t)32 * 1024 * 4;    // [1024][KP] bf16 pre-swizzled B^T (+bias rows)
constexpr size_t OFF_C1Q = OFF_BT;                             // [4][64][4096] uint2 bf16-pair slots (aliases BT)
constexpr size_t OFF_W1S = OFF_BT  + (size_t)1024 * KP * 2;    // [128][256] bf16 pre-swizzled fc1_w
constexpr size_t OFF_FSI = OFF_W1S + (size_t)128 * 256 * 2;    // [131072] f32 fs_ini
constexpr size_t OFF_FS  = OFF_FSI + (size_t)32 * 4096 * 4;    // [32][4096] f32 fs^T
constexpr size_t OFF_ASC = OFF_FS  + (size_t)32 * 4096 * 4;    // [4096][KP] bf16 A
constexpr size_t OFF_P1  = OFF_ASC + (size_t)4096 * KP * 2;    // [4096][1000] f16 K-split partial
// total = ~98.9 MB

// ---------------- kernel: transpose data [4096][256] -> dTp rows 1..256 ----------------
__global__ __launch_bounds__(256) void k_transpose(const float* __restrict__ data,
                                                   float* __restrict__ dTp) {
    __shared__ float tile[64][65];
    int bx = blockIdx.x & 63;
    int fx = blockIdx.x >> 6;
    int tx = threadIdx.x & 63, ty4 = threadIdx.x >> 6;
#pragma unroll
    for (int i = 0; i < 16; ++i) {
        int ty = ty4 * 16 + i;
        tile[ty][tx] = data[(bx * 64 + ty) * 256 + fx * 64 + tx];
    }
    __syncthreads();
#pragma unroll
    for (int i = 0; i < 16; ++i) {
        int ty = ty4 * 16 + i;
        dTp[(size_t)(fx * 64 + ty + 1) * 4096 + bx * 64 + tx] = tile[tx][ty];
    }
}

__global__ __launch_bounds__(256) void k_zrows(float* __restrict__ dTp) {
    int i = blockIdx.x * 256 + threadIdx.x;
    dTp[i] = 0.f;
    dTp[(size_t)257 * 4096 + i] = 0.f;
}

// ---------------- kernel: q1 = conv1(proto) - b1 ----------------
__global__ __launch_bounds__(256) void k_prep_proto(const float* __restrict__ proto,
                                                    const float* __restrict__ w1,
                                                    const float* __restrict__ b1,
                                                    float* __restrict__ q1p) {
    __shared__ float ps[256];
    __shared__ float w1s[20];
    int r = blockIdx.x, tid = threadIdx.x;
    ps[tid] = proto[r * 256 + tid];
    if (tid < 20) w1s[tid] = w1[tid];
    __syncthreads();
    if (tid < 254) {
#pragma unroll
        for (int c = 0; c < 4; ++c) {
            float s = -b1[c];
#pragma unroll
            for (int k = 0; k < 5; ++k) {
                int x = tid + k - 1;
                float xv = (x >= 0 && x < 256) ? ps[x] : 0.f;
                s += w1s[c * 5 + k] * xv;
            }
            q1p[r * 1024 + c * 256 + tid] = s;
        }
    }
}

// ---------------- kernel: c1q pair slots: slot j = (u32 at l=2j-1, u32 at l=2j) ----------------
// u32 at l = packed bf16 (conv1[c][2l], conv1[c][2l+1]). slot index = (l+1)>>1, comp = (l+1)&1.
__global__ __launch_bounds__(64) void k_prep_c1d(const float* __restrict__ dTp,
                                                 const float* __restrict__ w1,
                                                 unsigned* __restrict__ c1q) {
    int lane = threadIdx.x;
    int bg = blockIdx.x >> 3, ch = blockIdx.x & 7;
    int l0 = ch << 4;
    int nl = (ch == 7) ? 15 : 16;
    int b = (bg << 6) + lane;
    float w1r[20];
#pragma unroll
    for (int i = 0; i < 20; ++i) w1r[i] = w1[i];
    const float* dp = dTp + (size_t)(2 * l0) * 4096 + b;
    float d[6];
#pragma unroll
    for (int i = 0; i < 6; ++i) d[i] = dp[(size_t)i * 4096];
    dp += (size_t)6 * 4096;
    for (int li = 0; li < nl; ++li) {
        int l = l0 + li;
        int slot = (l + 1) >> 1, comp = (l + 1) & 1;
#pragma unroll
        for (int c = 0; c < 4; ++c) {
            float s0 = 0.f, s1 = 0.f;
#pragma unroll
            for (int k = 0; k < 5; ++k) {
                s0 += w1r[c * 5 + k] * d[k];
                s1 += w1r[c * 5 + k] * d[k + 1];
            }
            c1q[((size_t)(c * 64 + slot) * 4096 + b) * 2 + comp] =
                (unsigned)f2bf_rne(s0) | ((unsigned)f2bf_rne(s1) << 16);
        }
        d[0] = d[2]; d[1] = d[3]; d[2] = d[4]; d[3] = d[5];
        d[4] = dp[0];
        d[5] = dp[4096];
        dp += 8192;
    }
}

// ---------------- kernel: B^T cast via LDS tile (+bias rows at k>=8192) ----------------
__global__ __launch_bounds__(256) void k_castB(const float* __restrict__ cw,
                                               const float* __restrict__ cb,
                                               unsigned short* __restrict__ BT) {
    __shared__ unsigned short L[64 * 137];
    int tid = threadIdx.x;
    int kt = blockIdx.x >> 3, ct = blockIdx.x & 7;
    int k0 = kt << 6, c0 = ct << 7;
#pragma unroll
    for (int i = 0; i < 32; ++i) {
        int flat = i * 256 + tid;
        int cl = flat & 127, kl = flat >> 7;
        int cg = c0 + cl;
        int kg = k0 + kl;
        float v = 0.f;
        if (cg < 1000) {
            if (kg < 8192) v = cw[(size_t)kg * 1000 + cg];
            else if (kg < 8224) v = cb[(size_t)(kg - 8192) * 1000 + cg];
        }
        L[kl * 137 + cl] = f2bf_rne(v);
    }
    __syncthreads();
#pragma unroll
    for (int i = 0; i < 4; ++i) {
        int task = i * 256 + tid;
        int kg = task & 7, cl = task >> 3;
        int base = kg * 8 * 137 + cl;
        unsigned x = (unsigned)L[base] | ((unsigned)L[base + 137] << 16);
        unsigned y = (unsigned)L[base + 2 * 137] | ((unsigned)L[base + 3 * 137] << 16);
        unsigned z = (unsigned)L[base + 4 * 137] | ((unsigned)L[base + 5 * 137] << 16);
        unsigned w = (unsigned)L[base + 6 * 137] | ((unsigned)L[base + 7 * 137] << 16);
        uint4 o; o.x = x; o.y = y; o.z = z; o.w = w;
        int cg = c0 + cl;
        size_t byte = (size_t)cg * KROW + (size_t)(kt << 7) + (size_t)((kg ^ (cg & 7)) << 4);
        *(uint4*)((char*)BT + byte) = o;
    }
}

// ---------------- kernel: fc1_w cast -> pre-swizzled ----------------
__global__ __launch_bounds__(256) void k_castW(const float* __restrict__ fc1w,
                                               unsigned short* __restrict__ W1s) {
    int idx = blockIdx.x * 256 + threadIdx.x;
    int col = idx >> 8, k = idx & 255;
    float v = 0.f;
    if (col < 124 && k < 248) {
        int f = (k & 3) * 62 + (k >> 2);
        v = fc1w[f * 124 + col];
    }
    int byte = col * 512 + ((k >> 6) << 7) + ((((k >> 3) & 7) ^ (col & 7)) << 4) + ((k & 7) << 1);
    *(unsigned short*)((char*)W1s + byte) = f2bf_rne(v);
}

// ---------------- kernel: conv2 + fc1 + fc2 + tanh fused (4-wave blocks) ----------------
// r19 structure with ONE change: c1q uint2 pair-slots -> window advance = 1 uint2 load
// per channel (c1p VMEM per j2: 8 -> 4), loads hoisted to iteration top so the
// 80-pk_fma conv2 body covers their latency.
__global__ __launch_bounds__(256)
void k_convfc(const unsigned* __restrict__ c1qr,
              const float* __restrict__ q1p,
              const float* __restrict__ w2,
              const float* __restrict__ b2,
              const char* __restrict__ W1s,
              const float* __restrict__ fc1b,
              const float* __restrict__ fc2w,
              const float* __restrict__ fc2b,
              float* __restrict__ fsiniT) {
    __shared__ unsigned short T[64 * 264];   // 33,792 B

    int tid = threadIdx.x;
    int w = tid >> 6, lane = tid & 63;
    int r  = blockIdx.x >> 6;
    int b0 = (blockIdx.x & 63) << 6;
    int j2s = w << 4;

    // ---- phase A: conv2 (rolling window; paired c1q loads) ----
    {
        float w2r[80];
#pragma unroll
        for (int i = 0; i < 80; ++i) w2r[i] = w2[i];
        v2f bb[4];
#pragma unroll
        for (int c = 0; c < 4; ++c) { float t = b2[c]; bb[c][0] = t; bb[c][1] = t; }

        const float* q1row = q1p + r * 1024;
        const uint2* cpq = (const uint2*)c1qr + b0 + lane;   // index: (c*64+slot)*4096

        // pooled from packed u32 conv pair + q at l
        auto poolU = [&](unsigned u, int c, int l) -> float {
            float2 q = *(const float2*)(q1row + c * 256 + 2 * l);
            float vx = __uint_as_float(u << 16);
            float vy = __uint_as_float(u & 0xffff0000u);
            return 0.5f * (fmaxf(vx - q.x, 0.f) + fmaxf(vy - q.y, 0.f));
        };

        v2f P[4][5];
#pragma unroll
        for (int c = 0; c < 4; ++c) {
            uint2 s0 = cpq[(size_t)(c * 64 + j2s) * 4096];
            uint2 s1 = cpq[(size_t)(c * 64 + j2s + 1) * 4096];
            uint2 s2 = cpq[(size_t)(c * 64 + j2s + 2) * 4096];
            float pv[6];
            pv[0] = (j2s == 0) ? 0.f : poolU(s0.x, c, 2 * j2s - 1);
            pv[1] = poolU(s0.y, c, 2 * j2s);
            pv[2] = poolU(s1.x, c, 2 * j2s + 1);
            pv[3] = poolU(s1.y, c, 2 * j2s + 2);
            pv[4] = poolU(s2.x, c, 2 * j2s + 3);
            pv[5] = poolU(s2.y, c, 2 * j2s + 4);
#pragma unroll
            for (int k = 0; k < 5; ++k) { P[c][k][0] = pv[k]; P[c][k][1] = pv[k + 1]; }
        }

        int cnt = (w == 3) ? 14 : 16;
        int j2 = j2s;
#pragma unroll 1
        for (int jj = 0; jj < cnt; ++jj) {
            // hoisted advance loads (slot j2+3 = (l=2j2+5, l=2j2+6)); covered by conv2 math
            uint2 nx[4]; float2 qa[4], qb[4];
            bool adv = (jj < cnt - 1);
            if (adv) {
#pragma unroll
                for (int c = 0; c < 4; ++c) {
                    nx[c] = cpq[(size_t)(c * 64 + j2 + 3) * 4096];
                    qa[c] = *(const float2*)(q1row + c * 256 + 4 * j2 + 10);
                    qb[c] = *(const float2*)(q1row + c * 256 + 4 * j2 + 12);
                }
            }
            // conv2 (+b2) at t=2j2, 2j2+1: 80 pk_fma
            v2f u[4];
#pragma unroll
            for (int c = 0; c < 4; ++c) u[c] = bb[c];
#pragma unroll
            for (int c = 0; c < 4; ++c)
#pragma unroll
                for (int ci = 0; ci < 4; ++ci)
#pragma unroll
                    for (int k = 0; k < 5; ++k)
                        u[c] += P[ci][k] * w2r[(c * 4 + ci) * 5 + k];
            {
                float h0 = 0.5f * (fmaxf(u[0][0], 0.f) + fmaxf(u[0][1], 0.f));
                float h1 = 0.5f * (fmaxf(u[1][0], 0.f) + fmaxf(u[1][1], 0.f));
                float h2v = 0.5f * (fmaxf(u[2][0], 0.f) + fmaxf(u[2][1], 0.f));
                float h3 = 0.5f * (fmaxf(u[3][0], 0.f) + fmaxf(u[3][1], 0.f));
                uint2 vv;
                vv.x = (unsigned)f2bf_rne(h0) | ((unsigned)f2bf_rne(h1) << 16);
                vv.y = (unsigned)f2bf_rne(h2v) | ((unsigned)f2bf_rne(h3) << 16);
                *(uint2*)(T + lane * 264 + j2 * 4) = vv;
            }
            if (adv) {
#pragma unroll
                for (int c = 0; c < 4; ++c) {
                    float ax = __uint_as_float(nx[c].x << 16);
                    float ay = __uint_as_float(nx[c].x & 0xffff0000u);
                    float bx = __uint_as_float(nx[c].y << 16);
                    float by = __uint_as_float(nx[c].y & 0xffff0000u);
                    float n0 = 0.5f * (fmaxf(ax - qa[c].x, 0.f) + fmaxf(ay - qa[c].y, 0.f));
                    float n1 = 0.5f * (fmaxf(bx - qb[c].x, 0.f) + fmaxf(by - qb[c].y, 0.f));
                    v2f p4v = P[c][4];
                    P[c][0] = P[c][2]; P[c][1] = P[c][3]; P[c][2] = p4v;
                    v2f t3; t3[0] = p4v[1]; t3[1] = n0;
                    v2f t4; t4[0] = n0;     t4[1] = n1;
                    P[c][3] = t3; P[c][4] = t4;
                }
            }
            ++j2;
        }
        if (w == 3) {   // zero-pad k 248..255
            uint4 z; z.x = z.y = z.z = z.w = 0u;
            *(uint4*)(T + lane * 264 + 248) = z;
        }
    }
    __syncthreads();

    // ---- phase B: fc1 + relu + fc2 + tanh (16-row M-tile per wave) ----
    {
        int row0 = w << 4;   // 0,16,32,48
        int lr = lane & 15, g = lane >> 4, rxor = lr & 7;

        f32x4 acc[8] = {};

        const unsigned short* trow = T + (row0 + lr) * 264;

        auto inrowf = [&](int ks) {
            return ((ks >> 1) << 7) + ((((ks * 4 + g) & 7) ^ rxor) << 4);
        };

#pragma unroll
        for (int ks = 0; ks < 8; ++ks) {
            int koff = ks * 32 + g * 8;
            bf16x8 a0 = *(const bf16x8*)(trow + koff);
            int ir = inrowf(ks);
            bf16x8 bfr[8];
#pragma unroll
            for (int nf = 0; nf < 8; ++nf)
                bfr[nf] = *(const bf16x8*)(W1s + (nf * 16 + lr) * 512 + ir);
#pragma unroll
            for (int nf = 0; nf < 8; ++nf)
                acc[nf] = __builtin_amdgcn_mfma_f32_16x16x32_bf16(a0, bfr[nf], acc[nf], 0, 0, 0);
        }

        float zp[4] = {};
#pragma unroll
        for (int nf = 0; nf < 8; ++nf) {
            int col = nf * 16 + lr;
            float b1v = (col < 124) ? fc1b[col] : 0.f;
            float w2v = (col < 124) ? fc2w[col] : 0.f;
#pragma unroll
            for (int q = 0; q < 4; ++q) {
                float h = fmaxf(acc[nf][q] + b1v, 0.f);
                zp[q] += h * w2v;
            }
        }
#pragma unroll
        for (int off = 1; off < 16; off <<= 1) {
#pragma unroll
            for (int q = 0; q < 4; ++q)
                zp[q] += __shfl_xor(zp[q], off, 64);
        }
        if (lr == 0) {
            float c2 = fc2b[0];
            int sbase = r * 4096 + b0 + row0;
#pragma unroll
            for (int q = 0; q < 4; ++q) {
                int srow = sbase + g * 4 + q;
                fsiniT[srow] = tanhf(zp[q] + c2);
            }
        }
    }
}

// ---------------- kernel: softmax over rules ----------------
__global__ __launch_bounds__(256) void k_softmax(const float* __restrict__ fsiniT,
                                                 float* __restrict__ fsT) {
    int b = blockIdx.x * 256 + threadIdx.x;
    float v[32];
    float m = -1e30f;
#pragma unroll
    for (int r = 0; r < 32; ++r) { v[r] = fsiniT[r * 4096 + b]; m = fmaxf(m, v[r]); }
    float s = 0.f;
#pragma unroll
    for (int r = 0; r < 32; ++r) { v[r] = expf(v[r] - m); s += v[r]; }
    float inv = 1.f / s;
#pragma unroll
    for (int r = 0; r < 32; ++r) fsT[r * 4096 + b] = v[r] * inv;
}

// ---------------- kernel: A[b][k], pre-swizzled; k<8192: fs*data, 8192..8223: fs, rest 0 ----------------
__global__ __launch_bounds__(256) void k_scaleA(const float* __restrict__ data,
                                                const float* __restrict__ fsT,
                                                unsigned short* __restrict__ Asc) {
    int g = blockIdx.x * 256 + threadIdx.x;
    int b = g / 1040, kg = g - b * 1040;
    uint4 o;
    unsigned* op = (unsigned*)&o;
    if (kg < 1024) {
        int r = kg >> 5, f0 = (kg & 31) << 3;
        float fs = fsT[r * 4096 + b];
        const float4* dp = (const float4*)(data + b * 256 + f0);
        float4 v0 = dp[0], v1 = dp[1];
        float vals[8] = {v0.x, v0.y, v0.z, v0.w, v1.x, v1.y, v1.z, v1.w};
#pragma unroll
        for (int i = 0; i < 4; ++i) {
            unsigned lo = f2bf_rne(vals[2 * i] * fs);
            unsigned hi = f2bf_rne(vals[2 * i + 1] * fs);
            op[i] = lo | (hi << 16);
        }
    } else {
        int base = (kg - 1024) << 3;
        op[0] = op[1] = op[2] = op[3] = 0u;
        if (base < 32) {
#pragma unroll
            for (int i = 0; i < 4; ++i) {
                unsigned lo = f2bf_rne(fsT[(base + 2 * i) * 4096 + b]);
                unsigned hi = f2bf_rne(fsT[(base + 2 * i + 1) * 4096 + b]);
                op[i] = lo | (hi << 16);
            }
        }
    }
    size_t byte = (size_t)b * KROW + (size_t)((kg & ~7) << 4) + (size_t)(((kg & 7) ^ (b & 7)) << 4);
    *(uint4*)((char*)Asc + byte) = o;
}

// ---------------- kernel: GEMM [4096 x KP] x [KP x 1024], K-split 2, bias folded in ----------------
__global__ __launch_bounds__(512) void k_gemm(const unsigned short* __restrict__ Asc,
                                              const unsigned short* __restrict__ BT,
                                              float* __restrict__ out,
                                              _Float16* __restrict__ part1) {
    __shared__ unsigned short As[2][8192];
    __shared__ unsigned short Bs[2][8192];
    int tid = threadIdx.x, lane = tid & 63, w = tid >> 6;
    int wm = w >> 2, wn = w & 3;
    int bid = blockIdx.x;
    int xcd = bid & 7, idx = bid >> 3;
    int mt = (xcd << 2) | (idx >> 4);
    int nt = (idx >> 1) & 7;
    int ks = idx & 1;
    int row0 = mt << 7, col0 = nt << 7;

    f32x4 acc[4][2] = {};

    const char* Ab = (const char*)Asc + (size_t)ks * (KP);
    const char* Bb = (const char*)BT + (size_t)ks * (KP);
    int flat0 = tid * 16, flat1 = tid * 16 + 8192;
    int rowl0 = flat0 >> 7, colB0 = flat0 & 127;
    int rowl1 = flat1 >> 7, colB1 = flat1 & 127;
    const char* aSrc0 = Ab + (size_t)(row0 + rowl0) * KROW + colB0;
    const char* aSrc1 = Ab + (size_t)(row0 + rowl1) * KROW + colB1;
    const char* bSrc0 = Bb + (size_t)(col0 + rowl0) * KROW + colB0;
    const char* bSrc1 = Bb + (size_t)(col0 + rowl1) * KROW + colB1;

    auto stage = [&](int buf, int kt) {
        int off = kt << 7;
        gload_lds16(aSrc0 + off, (char*)&As[buf][0] + flat0);
        gload_lds16(aSrc1 + off, (char*)&As[buf][0] + flat1);
        gload_lds16(bSrc0 + off, (char*)&Bs[buf][0] + flat0);
        gload_lds16(bSrc1 + off, (char*)&Bs[buf][0] + flat1);
    };

    auto compute = [&](int buf) {
        const char* Asb = (const char*)&As[buf][0];
        const char* Bsb = (const char*)&Bs[buf][0];
#pragma unroll
        for (int s = 0; s < 2; ++s) {
            bf16x8 af[4], bfv[2];
            int colByte = ((s << 5) + ((lane >> 4) << 3)) << 1;
#pragma unroll
            for (int mi = 0; mi < 4; ++mi) {
                int rowA = (wm << 6) + (mi << 4) + (lane & 15);
                int byte = (rowA << 7) + colByte;
                af[mi] = *(const bf16x8*)(Asb + (byte ^ ((rowA & 7) << 4)));
            }
#pragma unroll
            for (int ni = 0; ni < 2; ++ni) {
                int rowB = (wn << 5) + (ni << 4) + (lane & 15);
                int byte = (rowB << 7) + colByte;
                bfv[ni] = *(const bf16x8*)(Bsb + (byte ^ ((rowB & 7) << 4)));
            }
#pragma unroll
            for (int mi = 0; mi < 4; ++mi)
#pragma unroll
                for (int ni = 0; ni < 2; ++ni)
                    acc[mi][ni] = __builtin_amdgcn_mfma_f32_16x16x32_bf16(af[mi], bfv[ni], acc[mi][ni], 0, 0, 0);
        }
    };

    stage(0, 0);
    asm volatile("s_waitcnt vmcnt(0)" ::: "memory");
    __syncthreads();
#pragma unroll 1
    for (int kt = 0; kt < 64; ++kt) {
        stage((kt + 1) & 1, kt + 1);
        compute(kt & 1);
        asm volatile("s_waitcnt vmcnt(0)" ::: "memory");
        __syncthreads();
    }
    compute(0);

    int cA = col0 + (wn << 5) + (lane & 15);
    int cB2 = cA + 16;
    int rbase = row0 + (wm << 6) + ((lane >> 4) << 2);

    if (ks == 0) {
#pragma unroll
        for (int mi = 0; mi < 4; ++mi)
#pragma unroll
            for (int q = 0; q < 4; ++q) {
                int row = rbase + mi * 16 + q;
                if (cA < 1000) out[row * 1000 + cA] = acc[mi][0][q];
                if (cB2 < 1000) out[row * 1000 + cB2] = acc[mi][1][q];
            }
    } else {
#pragma unroll
        for (int mi = 0; mi < 4; ++mi)
#pragma unroll
            for (int q = 0; q < 4; ++q) {
                int row = rbase + mi * 16 + q;
                if (cA < 1000) part1[row * 1000 + cA] = (_Float16)acc[mi][0][q];
                if (cB2 < 1000) part1[row * 1000 + cB2] = (_Float16)acc[mi][1][q];
            }
    }
}

// ---------------- kernel: out += part1 ----------------
__global__ __launch_bounds__(256) void k_reduce(float* __restrict__ out,
                                                const _Float16* __restrict__ p1) {
    int i = (blockIdx.x * 256 + threadIdx.x) * 4;
    float4 o = *(float4*)(out + i);
    o.x += (float)p1[i];
    o.y += (float)p1[i + 1];
    o.z += (float)p1[i + 2];
    o.w += (float)p1[i + 3];
    *(float4*)(out + i) = o;
}

// ---------------- launch ----------------
extern "C" void kernel_launch(void* const* d_in, const int* in_sizes, int n_in,
                              void* d_out, int out_size, void* d_ws, size_t ws_size,
                              hipStream_t stream) {
    const float* data  = (const float*)d_in[0];
    const float* proto = (const float*)d_in[1];
    const float* w1    = (const float*)d_in[2];
    const float* b1    = (const float*)d_in[3];
    const float* w2    = (const float*)d_in[4];
    const float* b2    = (const float*)d_in[5];
    const float* fc1w  = (const float*)d_in[6];
    const float* fc1b  = (const float*)d_in[7];
    const float* fc2w  = (const float*)d_in[8];
    const float* fc2b  = (const float*)d_in[9];
    const float* cw    = (const float*)d_in[10];
    const float* cbias = (const float*)d_in[11];
    float* out = (float*)d_out;
    char* ws = (char*)d_ws;

    float* dTp             = (float*)(ws + OFF_DT);
    float* q1p             = (float*)(ws + OFF_Q1);
    unsigned* c1q          = (unsigned*)(ws + OFF_C1Q);
    unsigned short* BT     = (unsigned short*)(ws + OFF_BT);
    unsigned short* W1s    = (unsigned short*)(ws + OFF_W1S);
    float* fsiniT          = (float*)(ws + OFF_FSI);
    float* fsT             = (float*)(ws + OFF_FS);
    unsigned short* Asc    = (unsigned short*)(ws + OFF_ASC);
    _Float16* part1        = (_Float16*)(ws + OFF_P1);

    hipLaunchKernelGGL(k_transpose, dim3(256), dim3(256), 0, stream, data, dTp);
    hipLaunchKernelGGL(k_zrows, dim3(16), dim3(256), 0, stream, dTp);
    hipLaunchKernelGGL(k_prep_proto, dim3(32), dim3(256), 0, stream, proto, w1, b1, q1p);
    hipLaunchKernelGGL(k_prep_c1d, dim3(512), dim3(64), 0, stream, dTp, w1, c1q);
    hipLaunchKernelGGL(k_castW, dim3(128), dim3(256), 0, stream, fc1w, W1s);
    hipLaunchKernelGGL(k_convfc, dim3(2048), dim3(256), 0, stream,
                       c1q, q1p, w2, b2, (const char*)W1s, fc1b, fc2w, fc2b, fsiniT);
    // castB AFTER convfc: BT region aliases c1q
    hipLaunchKernelGGL(k_castB, dim3(1040), dim3(256), 0, stream, cw, cbias, BT);
    hipLaunchKernelGGL(k_softmax, dim3(16), dim3(256), 0, stream, fsiniT, fsT);
    hipLaunchKernelGGL(k_scaleA, dim3(16640), dim3(256), 0, stream, data, fsT, Asc);
    hipLaunchKernelGGL(k_gemm, dim3(512), dim3(512), 0, stream, Asc, BT, out, part1);
    hipLaunchKernelGGL(k_reduce, dim3(4000), dim3(256), 0, stream, out, part1);
}

// Round 21
// 226.070 us; speedup vs baseline: 1.7341x; 1.0364x over previous
//
#include <hip/hip_runtime.h>
#include <hip/hip_bf16.h>

// ---------------- types / helpers ----------------
using bf16x8 = __attribute__((ext_vector_type(8))) short;
using f32x4  = __attribute__((ext_vector_type(4))) float;
using v2f    = __attribute__((ext_vector_type(2))) float;

__device__ __forceinline__ unsigned short f2bf_rne(float x) {
    unsigned u = __float_as_uint(x);
    u += 0x7fffu + ((u >> 16) & 1u);
    return (unsigned short)(u >> 16);
}

__device__ __forceinline__ void gload_lds16(const void* g, void* l) {
    __builtin_amdgcn_global_load_lds(
        (const __attribute__((address_space(1))) unsigned int*)g,
        (__attribute__((address_space(3))) unsigned int*)l, 16, 0, 0);
}

// K geometry: 8192 data k + 32 bias rows (fs x consq_b) + zero-pad -> 8320 = 2 x 65 x 64
constexpr int KP = 8320;
constexpr int KROW = KP * 2;

// ---------------- workspace layout (bytes) ----------------
constexpr size_t OFF_DT  = 0;                                  // [260][4096] f32 padded dataT
constexpr size_t OFF_Q1  = OFF_DT  + (size_t)260 * 4096 * 4;   // [32][4][256] f32 q1
constexpr size_t OFF_BT  = OFF_Q1  + (size_t)32 * 1024 * 4;    // [1024][KP] bf16 pre-swizzled B^T (+bias rows)
constexpr size_t OFF_C1Q = OFF_BT;                             // [4][64][4096] uint2 bf16-pair slots (aliases BT)
constexpr size_t OFF_W1S = OFF_BT  + (size_t)1024 * KP * 2;    // [128][256] bf16 pre-swizzled fc1_w
constexpr size_t OFF_FSI = OFF_W1S + (size_t)128 * 256 * 2;    // [131072] f32 fs_ini
constexpr size_t OFF_FS  = OFF_FSI + (size_t)32 * 4096 * 4;    // [32][4096] f32 fs^T
constexpr size_t OFF_ASC = OFF_FS  + (size_t)32 * 4096 * 4;    // [4096][KP] bf16 A
constexpr size_t OFF_P1  = OFF_ASC + (size_t)4096 * KP * 2;    // [4096][1000] f16 K-split partial
// total = ~98.9 MB

// ---------------- kernel: transpose data [4096][256] -> dTp rows 1..256 ----------------
__global__ __launch_bounds__(256) void k_transpose(const float* __restrict__ data,
                                                   float* __restrict__ dTp) {
    __shared__ float tile[64][65];
    int bx = blockIdx.x & 63;
    int fx = blockIdx.x >> 6;
    int tx = threadIdx.x & 63, ty4 = threadIdx.x >> 6;
#pragma unroll
    for (int i = 0; i < 16; ++i) {
        int ty = ty4 * 16 + i;
        tile[ty][tx] = data[(bx * 64 + ty) * 256 + fx * 64 + tx];
    }
    __syncthreads();
#pragma unroll
    for (int i = 0; i < 16; ++i) {
        int ty = ty4 * 16 + i;
        dTp[(size_t)(fx * 64 + ty + 1) * 4096 + bx * 64 + tx] = tile[tx][ty];
    }
}

__global__ __launch_bounds__(256) void k_zrows(float* __restrict__ dTp) {
    int i = blockIdx.x * 256 + threadIdx.x;
    dTp[i] = 0.f;
    dTp[(size_t)257 * 4096 + i] = 0.f;
}

// ---------------- kernel: q1 = conv1(proto) - b1 ----------------
__global__ __launch_bounds__(256) void k_prep_proto(const float* __restrict__ proto,
                                                    const float* __restrict__ w1,
                                                    const float* __restrict__ b1,
                                                    float* __restrict__ q1p) {
    __shared__ float ps[256];
    __shared__ float w1s[20];
    int r = blockIdx.x, tid = threadIdx.x;
    ps[tid] = proto[r * 256 + tid];
    if (tid < 20) w1s[tid] = w1[tid];
    __syncthreads();
    if (tid < 254) {
#pragma unroll
        for (int c = 0; c < 4; ++c) {
            float s = -b1[c];
#pragma unroll
            for (int k = 0; k < 5; ++k) {
                int x = tid + k - 1;
                float xv = (x >= 0 && x < 256) ? ps[x] : 0.f;
                s += w1s[c * 5 + k] * xv;
            }
            q1p[r * 1024 + c * 256 + tid] = s;
        }
    }
}

// ---------------- kernel: c1q pair slots: slot j = (u32 at l=2j-1, u32 at l=2j) ----------------
// u32 at l = packed bf16 (conv1[c][2l], conv1[c][2l+1]). slot index = (l+1)>>1, comp = (l+1)&1.
__global__ __launch_bounds__(64) void k_prep_c1d(const float* __restrict__ dTp,
                                                 const float* __restrict__ w1,
                                                 unsigned* __restrict__ c1q) {
    int lane = threadIdx.x;
    int bg = blockIdx.x >> 3, ch = blockIdx.x & 7;
    int l0 = ch << 4;
    int nl = (ch == 7) ? 15 : 16;
    int b = (bg << 6) + lane;
    float w1r[20];
#pragma unroll
    for (int i = 0; i < 20; ++i) w1r[i] = w1[i];
    const float* dp = dTp + (size_t)(2 * l0) * 4096 + b;
    float d[6];
#pragma unroll
    for (int i = 0; i < 6; ++i) d[i] = dp[(size_t)i * 4096];
    dp += (size_t)6 * 4096;
    for (int li = 0; li < nl; ++li) {
        int l = l0 + li;
        int slot = (l + 1) >> 1, comp = (l + 1) & 1;
#pragma unroll
        for (int c = 0; c < 4; ++c) {
            float s0 = 0.f, s1 = 0.f;
#pragma unroll
            for (int k = 0; k < 5; ++k) {
                s0 += w1r[c * 5 + k] * d[k];
                s1 += w1r[c * 5 + k] * d[k + 1];
            }
            c1q[((size_t)(c * 64 + slot) * 4096 + b) * 2 + comp] =
                (unsigned)f2bf_rne(s0) | ((unsigned)f2bf_rne(s1) << 16);
        }
        d[0] = d[2]; d[1] = d[3]; d[2] = d[4]; d[3] = d[5];
        d[4] = dp[0];
        d[5] = dp[4096];
        dp += 8192;
    }
}

// ---------------- kernel: B^T cast via LDS tile (+bias rows at k>=8192) ----------------
__global__ __launch_bounds__(256) void k_castB(const float* __restrict__ cw,
                                               const float* __restrict__ cb,
                                               unsigned short* __restrict__ BT) {
    __shared__ unsigned short L[64 * 137];
    int tid = threadIdx.x;
    int kt = blockIdx.x >> 3, ct = blockIdx.x & 7;
    int k0 = kt << 6, c0 = ct << 7;
#pragma unroll
    for (int i = 0; i < 32; ++i) {
        int flat = i * 256 + tid;
        int cl = flat & 127, kl = flat >> 7;
        int cg = c0 + cl;
        int kg = k0 + kl;
        float v = 0.f;
        if (cg < 1000) {
            if (kg < 8192) v = cw[(size_t)kg * 1000 + cg];
            else if (kg < 8224) v = cb[(size_t)(kg - 8192) * 1000 + cg];
        }
        L[kl * 137 + cl] = f2bf_rne(v);
    }
    __syncthreads();
#pragma unroll
    for (int i = 0; i < 4; ++i) {
        int task = i * 256 + tid;
        int kg = task & 7, cl = task >> 3;
        int base = kg * 8 * 137 + cl;
        unsigned x = (unsigned)L[base] | ((unsigned)L[base + 137] << 16);
        unsigned y = (unsigned)L[base + 2 * 137] | ((unsigned)L[base + 3 * 137] << 16);
        unsigned z = (unsigned)L[base + 4 * 137] | ((unsigned)L[base + 5 * 137] << 16);
        unsigned w = (unsigned)L[base + 6 * 137] | ((unsigned)L[base + 7 * 137] << 16);
        uint4 o; o.x = x; o.y = y; o.z = z; o.w = w;
        int cg = c0 + cl;
        size_t byte = (size_t)cg * KROW + (size_t)(kt << 7) + (size_t)((kg ^ (cg & 7)) << 4);
        *(uint4*)((char*)BT + byte) = o;
    }
}

// ---------------- kernel: fc1_w cast -> pre-swizzled ----------------
__global__ __launch_bounds__(256) void k_castW(const float* __restrict__ fc1w,
                                               unsigned short* __restrict__ W1s) {
    int idx = blockIdx.x * 256 + threadIdx.x;
    int col = idx >> 8, k = idx & 255;
    float v = 0.f;
    if (col < 124 && k < 248) {
        int f = (k & 3) * 62 + (k >> 2);
        v = fc1w[f * 124 + col];
    }
    int byte = col * 512 + ((k >> 6) << 7) + ((((k >> 3) & 7) ^ (col & 7)) << 4) + ((k & 7) << 1);
    *(unsigned short*)((char*)W1s + byte) = f2bf_rne(v);
}

// ---------------- kernel: conv2 + fc1 + fc2 + tanh fused (4-wave blocks) ----------------
// r20 structure with ONE change: q1 row staged to LDS (4 KB) once per block; phase-A q
// reads become wave-uniform ds_read broadcasts -> hot-loop VMEM ops 12 -> 4 per j2.
// LDS 37.9 KB -> still 4 blocks/CU.
__global__ __launch_bounds__(256)
void k_convfc(const unsigned* __restrict__ c1qr,
              const float* __restrict__ q1p,
              const float* __restrict__ w2,
              const float* __restrict__ b2,
              const char* __restrict__ W1s,
              const float* __restrict__ fc1b,
              const float* __restrict__ fc2w,
              const float* __restrict__ fc2b,
              float* __restrict__ fsiniT) {
    __shared__ unsigned short T[64 * 264];   // 33,792 B
    __shared__ float qs[1024];               //  4,096 B

    int tid = threadIdx.x;
    int w = tid >> 6, lane = tid & 63;
    int r  = blockIdx.x >> 6;
    int b0 = (blockIdx.x & 63) << 6;
    int j2s = w << 4;

    // stage q1 row (rule-uniform) into LDS: 256 thr x float4 = 4 KB
    {
        const float4* src = (const float4*)(q1p + r * 1024);
        ((float4*)qs)[tid] = src[tid];
    }
    __syncthreads();

    // ---- phase A: conv2 (rolling window; paired c1q loads; q from LDS) ----
    {
        float w2r[80];
#pragma unroll
        for (int i = 0; i < 80; ++i) w2r[i] = w2[i];
        v2f bb[4];
#pragma unroll
        for (int c = 0; c < 4; ++c) { float t = b2[c]; bb[c][0] = t; bb[c][1] = t; }

        const uint2* cpq = (const uint2*)c1qr + b0 + lane;   // index: (c*64+slot)*4096

        // pooled from packed u32 conv pair + q (LDS) at l
        auto poolU = [&](unsigned u, int c, int l) -> float {
            float2 q = *(const float2*)(qs + c * 256 + 2 * l);
            float vx = __uint_as_float(u << 16);
            float vy = __uint_as_float(u & 0xffff0000u);
            return 0.5f * (fmaxf(vx - q.x, 0.f) + fmaxf(vy - q.y, 0.f));
        };

        v2f P[4][5];
#pragma unroll
        for (int c = 0; c < 4; ++c) {
            uint2 s0 = cpq[(size_t)(c * 64 + j2s) * 4096];
            uint2 s1 = cpq[(size_t)(c * 64 + j2s + 1) * 4096];
            uint2 s2 = cpq[(size_t)(c * 64 + j2s + 2) * 4096];
            float pv[6];
            pv[0] = (j2s == 0) ? 0.f : poolU(s0.x, c, 2 * j2s - 1);
            pv[1] = poolU(s0.y, c, 2 * j2s);
            pv[2] = poolU(s1.x, c, 2 * j2s + 1);
            pv[3] = poolU(s1.y, c, 2 * j2s + 2);
            pv[4] = poolU(s2.x, c, 2 * j2s + 3);
            pv[5] = poolU(s2.y, c, 2 * j2s + 4);
#pragma unroll
            for (int k = 0; k < 5; ++k) { P[c][k][0] = pv[k]; P[c][k][1] = pv[k + 1]; }
        }

        int cnt = (w == 3) ? 14 : 16;
        int j2 = j2s;
#pragma unroll 1
        for (int jj = 0; jj < cnt; ++jj) {
            // hoisted advance loads (slot j2+3 = (l=2j2+5, l=2j2+6)); covered by conv2 math
            uint2 nx[4];
            bool adv = (jj < cnt - 1);
            if (adv) {
#pragma unroll
                for (int c = 0; c < 4; ++c)
                    nx[c] = cpq[(size_t)(c * 64 + j2 + 3) * 4096];
            }
            // conv2 (+b2) at t=2j2, 2j2+1: 80 pk_fma
            v2f u[4];
#pragma unroll
            for (int c = 0; c < 4; ++c) u[c] = bb[c];
#pragma unroll
            for (int c = 0; c < 4; ++c)
#pragma unroll
                for (int ci = 0; ci < 4; ++ci)
#pragma unroll
                    for (int k = 0; k < 5; ++k)
                        u[c] += P[ci][k] * w2r[(c * 4 + ci) * 5 + k];
            {
                float h0 = 0.5f * (fmaxf(u[0][0], 0.f) + fmaxf(u[0][1], 0.f));
                float h1 = 0.5f * (fmaxf(u[1][0], 0.f) + fmaxf(u[1][1], 0.f));
                float h2v = 0.5f * (fmaxf(u[2][0], 0.f) + fmaxf(u[2][1], 0.f));
                float h3 = 0.5f * (fmaxf(u[3][0], 0.f) + fmaxf(u[3][1], 0.f));
                uint2 vv;
                vv.x = (unsigned)f2bf_rne(h0) | ((unsigned)f2bf_rne(h1) << 16);
                vv.y = (unsigned)f2bf_rne(h2v) | ((unsigned)f2bf_rne(h3) << 16);
                *(uint2*)(T + lane * 264 + j2 * 4) = vv;
            }
            if (adv) {
#pragma unroll
                for (int c = 0; c < 4; ++c) {
                    float2 qa = *(const float2*)(qs + c * 256 + 4 * j2 + 10);
                    float2 qb = *(const float2*)(qs + c * 256 + 4 * j2 + 12);
                    float ax = __uint_as_float(nx[c].x << 16);
                    float ay = __uint_as_float(nx[c].x & 0xffff0000u);
                    float bx = __uint_as_float(nx[c].y << 16);
                    float by = __uint_as_float(nx[c].y & 0xffff0000u);
                    float n0 = 0.5f * (fmaxf(ax - qa.x, 0.f) + fmaxf(ay - qa.y, 0.f));
                    float n1 = 0.5f * (fmaxf(bx - qb.x, 0.f) + fmaxf(by - qb.y, 0.f));
                    v2f p4v = P[c][4];
                    P[c][0] = P[c][2]; P[c][1] = P[c][3]; P[c][2] = p4v;
                    v2f t3; t3[0] = p4v[1]; t3[1] = n0;
                    v2f t4; t4[0] = n0;     t4[1] = n1;
                    P[c][3] = t3; P[c][4] = t4;
                }
            }
            ++j2;
        }
        if (w == 3) {   // zero-pad k 248..255
            uint4 z; z.x = z.y = z.z = z.w = 0u;
            *(uint4*)(T + lane * 264 + 248) = z;
        }
    }
    __syncthreads();

    // ---- phase B: fc1 + relu + fc2 + tanh (16-row M-tile per wave) ----
    {
        int row0 = w << 4;   // 0,16,32,48
        int lr = lane & 15, g = lane >> 4, rxor = lr & 7;

        f32x4 acc[8] = {};

        const unsigned short* trow = T + (row0 + lr) * 264;

        auto inrowf = [&](int ks) {
            return ((ks >> 1) << 7) + ((((ks * 4 + g) & 7) ^ rxor) << 4);
        };

#pragma unroll
        for (int ks = 0; ks < 8; ++ks) {
            int koff = ks * 32 + g * 8;
            bf16x8 a0 = *(const bf16x8*)(trow + koff);
            int ir = inrowf(ks);
            bf16x8 bfr[8];
#pragma unroll
            for (int nf = 0; nf < 8; ++nf)
                bfr[nf] = *(const bf16x8*)(W1s + (nf * 16 + lr) * 512 + ir);
#pragma unroll
            for (int nf = 0; nf < 8; ++nf)
                acc[nf] = __builtin_amdgcn_mfma_f32_16x16x32_bf16(a0, bfr[nf], acc[nf], 0, 0, 0);
        }

        float zp[4] = {};
#pragma unroll
        for (int nf = 0; nf < 8; ++nf) {
            int col = nf * 16 + lr;
            float b1v = (col < 124) ? fc1b[col] : 0.f;
            float w2v = (col < 124) ? fc2w[col] : 0.f;
#pragma unroll
            for (int q = 0; q < 4; ++q) {
                float h = fmaxf(acc[nf][q] + b1v, 0.f);
                zp[q] += h * w2v;
            }
        }
#pragma unroll
        for (int off = 1; off < 16; off <<= 1) {
#pragma unroll
            for (int q = 0; q < 4; ++q)
                zp[q] += __shfl_xor(zp[q], off, 64);
        }
        if (lr == 0) {
            float c2 = fc2b[0];
            int sbase = r * 4096 + b0 + row0;
#pragma unroll
            for (int q = 0; q < 4; ++q) {
                int srow = sbase + g * 4 + q;
                fsiniT[srow] = tanhf(zp[q] + c2);
            }
        }
    }
}

// ---------------- kernel: softmax over rules ----------------
__global__ __launch_bounds__(256) void k_softmax(const float* __restrict__ fsiniT,
                                                 float* __restrict__ fsT) {
    int b = blockIdx.x * 256 + threadIdx.x;
    float v[32];
    float m = -1e30f;
#pragma unroll
    for (int r = 0; r < 32; ++r) { v[r] = fsiniT[r * 4096 + b]; m = fmaxf(m, v[r]); }
    float s = 0.f;
#pragma unroll
    for (int r = 0; r < 32; ++r) { v[r] = expf(v[r] - m); s += v[r]; }
    float inv = 1.f / s;
#pragma unroll
    for (int r = 0; r < 32; ++r) fsT[r * 4096 + b] = v[r] * inv;
}

// ---------------- kernel: A[b][k], pre-swizzled; k<8192: fs*data, 8192..8223: fs, rest 0 ----------------
__global__ __launch_bounds__(256) void k_scaleA(const float* __restrict__ data,
                                                const float* __restrict__ fsT,
                                                unsigned short* __restrict__ Asc) {
    int g = blockIdx.x * 256 + threadIdx.x;
    int b = g / 1040, kg = g - b * 1040;
    uint4 o;
    unsigned* op = (unsigned*)&o;
    if (kg < 1024) {
        int r = kg >> 5, f0 = (kg & 31) << 3;
        float fs = fsT[r * 4096 + b];
        const float4* dp = (const float4*)(data + b * 256 + f0);
        float4 v0 = dp[0], v1 = dp[1];
        float vals[8] = {v0.x, v0.y, v0.z, v0.w, v1.x, v1.y, v1.z, v1.w};
#pragma unroll
        for (int i = 0; i < 4; ++i) {
            unsigned lo = f2bf_rne(vals[2 * i] * fs);
            unsigned hi = f2bf_rne(vals[2 * i + 1] * fs);
            op[i] = lo | (hi << 16);
        }
    } else {
        int base = (kg - 1024) << 3;
        op[0] = op[1] = op[2] = op[3] = 0u;
        if (base < 32) {
#pragma unroll
            for (int i = 0; i < 4; ++i) {
                unsigned lo = f2bf_rne(fsT[(base + 2 * i) * 4096 + b]);
                unsigned hi = f2bf_rne(fsT[(base + 2 * i + 1) * 4096 + b]);
                op[i] = lo | (hi << 16);
            }
        }
    }
    size_t byte = (size_t)b * KROW + (size_t)((kg & ~7) << 4) + (size_t)(((kg & 7) ^ (b & 7)) << 4);
    *(uint4*)((char*)Asc + byte) = o;
}

// ---------------- kernel: GEMM [4096 x KP] x [KP x 1024], K-split 2, bias folded in ----------------
__global__ __launch_bounds__(512) void k_gemm(const unsigned short* __restrict__ Asc,
                                              const unsigned short* __restrict__ BT,
                                              float* __restrict__ out,
                                              _Float16* __restrict__ part1) {
    __shared__ unsigned short As[2][8192];
    __shared__ unsigned short Bs[2][8192];
    int tid = threadIdx.x, lane = tid & 63, w = tid >> 6;
    int wm = w >> 2, wn = w & 3;
    int bid = blockIdx.x;
    int xcd = bid & 7, idx = bid >> 3;
    int mt = (xcd << 2) | (idx >> 4);
    int nt = (idx >> 1) & 7;
    int ks = idx & 1;
    int row0 = mt << 7, col0 = nt << 7;

    f32x4 acc[4][2] = {};

    const char* Ab = (const char*)Asc + (size_t)ks * (KP);
    const char* Bb = (const char*)BT + (size_t)ks * (KP);
    int flat0 = tid * 16, flat1 = tid * 16 + 8192;
    int rowl0 = flat0 >> 7, colB0 = flat0 & 127;
    int rowl1 = flat1 >> 7, colB1 = flat1 & 127;
    const char* aSrc0 = Ab + (size_t)(row0 + rowl0) * KROW + colB0;
    const char* aSrc1 = Ab + (size_t)(row0 + rowl1) * KROW + colB1;
    const char* bSrc0 = Bb + (size_t)(col0 + rowl0) * KROW + colB0;
    const char* bSrc1 = Bb + (size_t)(col0 + rowl1) * KROW + colB1;

    auto stage = [&](int buf, int kt) {
        int off = kt << 7;
        gload_lds16(aSrc0 + off, (char*)&As[buf][0] + flat0);
        gload_lds16(aSrc1 + off, (char*)&As[buf][0] + flat1);
        gload_lds16(bSrc0 + off, (char*)&Bs[buf][0] + flat0);
        gload_lds16(bSrc1 + off, (char*)&Bs[buf][0] + flat1);
    };

    auto compute = [&](int buf) {
        const char* Asb = (const char*)&As[buf][0];
        const char* Bsb = (const char*)&Bs[buf][0];
#pragma unroll
        for (int s = 0; s < 2; ++s) {
            bf16x8 af[4], bfv[2];
            int colByte = ((s << 5) + ((lane >> 4) << 3)) << 1;
#pragma unroll
            for (int mi = 0; mi < 4; ++mi) {
                int rowA = (wm << 6) + (mi << 4) + (lane & 15);
                int byte = (rowA << 7) + colByte;
                af[mi] = *(const bf16x8*)(Asb + (byte ^ ((rowA & 7) << 4)));
            }
#pragma unroll
            for (int ni = 0; ni < 2; ++ni) {
                int rowB = (wn << 5) + (ni << 4) + (lane & 15);
                int byte = (rowB << 7) + colByte;
                bfv[ni] = *(const bf16x8*)(Bsb + (byte ^ ((rowB & 7) << 4)));
            }
#pragma unroll
            for (int mi = 0; mi < 4; ++mi)
#pragma unroll
                for (int ni = 0; ni < 2; ++ni)
                    acc[mi][ni] = __builtin_amdgcn_mfma_f32_16x16x32_bf16(af[mi], bfv[ni], acc[mi][ni], 0, 0, 0);
        }
    };

    stage(0, 0);
    asm volatile("s_waitcnt vmcnt(0)" ::: "memory");
    __syncthreads();
#pragma unroll 1
    for (int kt = 0; kt < 64; ++kt) {
        stage((kt + 1) & 1, kt + 1);
        compute(kt & 1);
        asm volatile("s_waitcnt vmcnt(0)" ::: "memory");
        __syncthreads();
    }
    compute(0);

    int cA = col0 + (wn << 5) + (lane & 15);
    int cB2 = cA + 16;
    int rbase = row0 + (wm << 6) + ((lane >> 4) << 2);

    if (ks == 0) {
#pragma unroll
        for (int mi = 0; mi < 4; ++mi)
#pragma unroll
            for (int q = 0; q < 4; ++q) {
                int row = rbase + mi * 16 + q;
                if (cA < 1000) out[row * 1000 + cA] = acc[mi][0][q];
                if (cB2 < 1000) out[row * 1000 + cB2] = acc[mi][1][q];
            }
    } else {
#pragma unroll
        for (int mi = 0; mi < 4; ++mi)
#pragma unroll
            for (int q = 0; q < 4; ++q) {
                int row = rbase + mi * 16 + q;
                if (cA < 1000) part1[row * 1000 + cA] = (_Float16)acc[mi][0][q];
                if (cB2 < 1000) part1[row * 1000 + cB2] = (_Float16)acc[mi][1][q];
            }
    }
}

// ---------------- kernel: out += part1 ----------------
__global__ __launch_bounds__(256) void k_reduce(float* __restrict__ out,
                                                const _Float16* __restrict__ p1) {
    int i = (blockIdx.x * 256 + threadIdx.x) * 4;
    float4 o = *(float4*)(out + i);
    o.x += (float)p1[i];
    o.y += (float)p1[i + 1];
    o.z += (float)p1[i + 2];
    o.w += (float)p1[i + 3];
    *(float4*)(out + i) = o;
}

// ---------------- launch ----------------
extern "C" void kernel_launch(void* const* d_in, const int* in_sizes, int n_in,
                              void* d_out, int out_size, void* d_ws, size_t ws_size,
                              hipStream_t stream) {
    const float* data  = (const float*)d_in[0];
    const float* proto = (const float*)d_in[1];
    const float* w1    = (const float*)d_in[2];
    const float* b1    = (const float*)d_in[3];
    const float* w2    = (const float*)d_in[4];
    const float* b2    = (const float*)d_in[5];
    const float* fc1w  = (const float*)d_in[6];
    const float* fc1b  = (const float*)d_in[7];
    const float* fc2w  = (const float*)d_in[8];
    const float* fc2b  = (const float*)d_in[9];
    const float* cw    = (const float*)d_in[10];
    const float* cbias = (const float*)d_in[11];
    float* out = (float*)d_out;
    char* ws = (char*)d_ws;

    float* dTp             = (float*)(ws + OFF_DT);
    float* q1p             = (float*)(ws + OFF_Q1);
    unsigned* c1q          = (unsigned*)(ws + OFF_C1Q);
    unsigned short* BT     = (unsigned short*)(ws + OFF_BT);
    unsigned short* W1s    = (unsigned short*)(ws + OFF_W1S);
    float* fsiniT          = (float*)(ws + OFF_FSI);
    float* fsT             = (float*)(ws + OFF_FS);
    unsigned short* Asc    = (unsigned short*)(ws + OFF_ASC);
    _Float16* part1        = (_Float16*)(ws + OFF_P1);

    hipLaunchKernelGGL(k_transpose, dim3(256), dim3(256), 0, stream, data, dTp);
    hipLaunchKernelGGL(k_zrows, dim3(16), dim3(256), 0, stream, dTp);
    hipLaunchKernelGGL(k_prep_proto, dim3(32), dim3(256), 0, stream, proto, w1, b1, q1p);
    hipLaunchKernelGGL(k_prep_c1d, dim3(512), dim3(64), 0, stream, dTp, w1, c1q);
    hipLaunchKernelGGL(k_castW, dim3(128), dim3(256), 0, stream, fc1w, W1s);
    hipLaunchKernelGGL(k_convfc, dim3(2048), dim3(256), 0, stream,
                       c1q, q1p, w2, b2, (const char*)W1s, fc1b, fc2w, fc2b, fsiniT);
    // castB AFTER convfc: BT region aliases c1q
    hipLaunchKernelGGL(k_castB, dim3(1040), dim3(256), 0, stream, cw, cbias, BT);
    hipLaunchKernelGGL(k_softmax, dim3(16), dim3(256), 0, stream, fsiniT, fsT);
    hipLaunchKernelGGL(k_scaleA, dim3(16640), dim3(256), 0, stream, data, fsT, Asc);
    hipLaunchKernelGGL(k_gemm, dim3(512), dim3(512), 0, stream, Asc, BT, out, part1);
    hipLaunchKernelGGL(k_reduce, dim3(4000), dim3(256), 0, stream, out, part1);
}